// Round 1
// baseline (731.025 us; speedup 1.0000x reference)
//
#include <hip/hip_runtime.h>
#include <hip/hip_bf16.h>
#include <math.h>

// ---------------------------------------------------------------------------
// Model constants
//   B=4, T=1024, F_IN=80, C0=256, C_EMB=512, HEADS=8, K=7, D_HEAD=64, MLP=2048
// ---------------------------------------------------------------------------

typedef __bf16 bf16x8 __attribute__((ext_vector_type(8)));
typedef float f32x4 __attribute__((ext_vector_type(4)));

static __device__ __forceinline__ short f2bf(float f) {
  __hip_bfloat16 h = __float2bfloat16(f);
  return __builtin_bit_cast(short, h);
}

static __device__ __forceinline__ float wave_sum(float v) {
#pragma unroll
  for (int o = 32; o; o >>= 1) v += __shfl_xor(v, o);
  return v;
}

// ---------------------------------------------------------------------------
// conv0 (1->256, 3x3, pad t +-1) + maxpool3(w) + relu.  x:[4,1,1024,80] fp32
// out h0 bf16 [4][256][1024][26]
// block = (b,t), 256 threads = one per output channel
// ---------------------------------------------------------------------------
__global__ __launch_bounds__(256) void conv0_kernel(
    const float* __restrict__ x, const float* __restrict__ w,
    const float* __restrict__ bias, short* __restrict__ h0) {
  const int b = blockIdx.x >> 10;
  const int t = blockIdx.x & 1023;
  const int c = threadIdx.x;
  __shared__ float xs[3][80];
  for (int i = threadIdx.x; i < 240; i += 256) {
    int dt = i / 80, f = i - dt * 80;
    int tt = t + dt - 1;
    xs[dt][f] = (tt >= 0 && tt < 1024) ? x[(b * 1024 + tt) * 80 + f] : 0.f;
  }
  float wr[9];
#pragma unroll
  for (int i = 0; i < 9; ++i) wr[i] = w[c * 9 + i];
  const float bi = bias[c];
  __syncthreads();
  short* out = &h0[((size_t)(b * 256 + c) * 1024 + t) * 26];
  for (int fo = 0; fo < 26; ++fo) {
    float m = -1e30f;
#pragma unroll
    for (int p = 0; p < 3; ++p) {
      const int f = fo * 3 + p;
      float acc = bi;
#pragma unroll
      for (int dt = 0; dt < 3; ++dt)
#pragma unroll
        for (int df = 0; df < 3; ++df)
          acc += xs[dt][f + df] * wr[dt * 3 + df];
      m = fmaxf(m, acc);
    }
    out[fo] = f2bf(fmaxf(m, 0.f));
  }
}

// ---------------------------------------------------------------------------
// Weight pre-transposes (fp32 -> bf16, once per launch)
// ---------------------------------------------------------------------------
// conv1_w [512][256][1][12] -> wt1 [co][kw][ci] bf16
__global__ __launch_bounds__(256) void prep_w1(const float* __restrict__ w,
                                               short* __restrict__ wt) {
  const int co = blockIdx.x;
  __shared__ float ls[3072];
  for (int i = threadIdx.x; i < 3072; i += 256) ls[i] = w[co * 3072 + i];
  __syncthreads();
  for (int i = threadIdx.x; i < 3072; i += 256) {
    int kw = i >> 8, ci = i & 255;
    wt[co * 3072 + i] = f2bf(ls[ci * 12 + kw]);
  }
}

// conv2_w [512][512][3][3] -> wt2 [co][p=dt*3+dw][ci] bf16
__global__ __launch_bounds__(256) void prep_w2(const float* __restrict__ w,
                                               short* __restrict__ wt) {
  const int co = blockIdx.x;
  __shared__ float ls[4608];
  for (int i = threadIdx.x; i < 4608; i += 256) ls[i] = w[co * 4608 + i];
  __syncthreads();
  for (int i = threadIdx.x; i < 4608; i += 256) {
    int p = i >> 9, ci = i & 511;
    wt[co * 4608 + i] = f2bf(ls[ci * 9 + p]);
  }
}

// dense W [K][N] fp32 -> Wt [N][K] bf16 (tiled transpose)
__global__ void prep_wt(const float* __restrict__ w, short* __restrict__ wt,
                        int K, int N) {
  __shared__ float tile[32][33];
  const int k0 = blockIdx.x * 32, n0 = blockIdx.y * 32;
  const int tx = threadIdx.x, ty = threadIdx.y;
  for (int r = ty; r < 32; r += 8) tile[r][tx] = w[(size_t)(k0 + r) * N + n0 + tx];
  __syncthreads();
  for (int r = ty; r < 32; r += 8) wt[(size_t)(n0 + r) * K + k0 + tx] = f2bf(tile[tx][r]);
}

// ---------------------------------------------------------------------------
// conv1 (256->512, 1x12) + pool3 + relu via MFMA GEMM.
// h0 bf16 [4][256][1024][26] -> h1 bf16 [4][512][1024][5]
// Block: co_tile=128, t_tile=8 (N = 8t * 16w, w=15 is pad). 4 waves 2x2.
// K-loop: outer ci-chunk (8 x 32ci, X staged transposed), inner kw (12).
// ---------------------------------------------------------------------------
__global__ __launch_bounds__(256) void conv1_kernel(
    const short* __restrict__ h0, const short* __restrict__ wt1,
    const float* __restrict__ bias, short* __restrict__ h1) {
  const int bt = blockIdx.x;       // 0..511
  const int b = bt >> 7;
  const int t0 = (bt & 127) * 8;
  const int co0 = blockIdx.y * 128;
  __shared__ short Xst[8][28][40];   // [t][w(0..27, 26/27 zero)][ci(+pad)]
  __shared__ short As[128][40];      // [co][ci(+pad)]
  const int tid = threadIdx.x;
  const int wid = tid >> 6, lane = tid & 63;
  const int wm = wid >> 1, wn = wid & 1;
  const int l15 = lane & 15, lg = lane >> 4;

  const f32x4 zf = {0.f, 0.f, 0.f, 0.f};
  f32x4 acc[4][4];
#pragma unroll
  for (int i = 0; i < 4; ++i)
#pragma unroll
    for (int j = 0; j < 4; ++j) acc[i][j] = zf;

  const int sci = tid >> 3, stl = tid & 7;       // X staging role
  const int aco = tid >> 1, ahf = (tid & 1) * 16; // A staging role

  for (int cc = 0; cc < 8; ++cc) {
    const int ci0 = cc * 32;
    __syncthreads();  // previous iteration's reads done
    {
      const unsigned int* src = reinterpret_cast<const unsigned int*>(
          &h0[((size_t)(b * 256 + ci0 + sci) * 1024 + t0 + stl) * 26]);
      short* dst = &Xst[stl][0][sci];
#pragma unroll
      for (int u = 0; u < 13; ++u) {
        unsigned int pr = src[u];
        dst[(2 * u) * 40] = (short)(pr & 0xffff);
        dst[(2 * u + 1) * 40] = (short)(pr >> 16);
      }
      dst[26 * 40] = 0;
      dst[27 * 40] = 0;
    }
    for (int kw = 0; kw < 12; ++kw) {
      __syncthreads();  // Xst ready / previous As reads done
      {
        const int4* s = reinterpret_cast<const int4*>(
            &wt1[((co0 + aco) * 12 + kw) * 256 + ci0 + ahf]);
        int4* d = reinterpret_cast<int4*>(&As[aco][ahf]);
        d[0] = s[0];
        d[1] = s[1];
      }
      __syncthreads();
      bf16x8 bfr[4];
#pragma unroll
      for (int sn = 0; sn < 4; ++sn) {
        const int tl = wn * 4 + sn;
        bfr[sn] = *reinterpret_cast<const bf16x8*>(&Xst[tl][l15 + kw][lg * 8]);
      }
#pragma unroll
      for (int sm = 0; sm < 4; ++sm) {
        bf16x8 a = *reinterpret_cast<const bf16x8*>(&As[wm * 64 + sm * 16 + l15][lg * 8]);
#pragma unroll
        for (int sn = 0; sn < 4; ++sn)
          acc[sm][sn] = __builtin_amdgcn_mfma_f32_16x16x32_bf16(a, bfr[sn], acc[sm][sn], 0, 0, 0);
      }
    }
  }
  // epilogue: pool w-triples (within 16-lane groups) + bias + relu
  const int basel = lane & 48;
  const int wsrc = (l15 < 5) ? 3 * l15 : 0;
#pragma unroll
  for (int sm = 0; sm < 4; ++sm) {
#pragma unroll
    for (int sn = 0; sn < 4; ++sn) {
      const int tl = wn * 4 + sn;
#pragma unroll
      for (int r = 0; r < 4; ++r) {
        float val = acc[sm][sn][r];
        float v0 = __shfl(val, basel + wsrc);
        float v1 = __shfl(val, basel + wsrc + 1);
        float v2 = __shfl(val, basel + wsrc + 2);
        if (l15 < 5) {
          const int co = co0 + wm * 64 + sm * 16 + lg * 4 + r;
          float p = fmaxf(fmaxf(v0, v1), v2) + bias[co];
          h1[((size_t)(b * 512 + co) * 1024 + t0 + tl) * 5 + l15] = f2bf(fmaxf(p, 0.f));
        }
      }
    }
  }
}

// ---------------------------------------------------------------------------
// conv2 (512->512, 3x3, pad t +-1) + pool3 + relu via MFMA GEMM, output
// transposed: emb_in fp32 [b][t][512].
// Block: co_tile=128, t_tile=32 (96 packed cols = t*3+w). 4 waves 2x2.
// ---------------------------------------------------------------------------
__global__ __launch_bounds__(256) void conv2_kernel(
    const short* __restrict__ h1, const short* __restrict__ wt2,
    const float* __restrict__ bias, float* __restrict__ emb_in) {
  const int bt = blockIdx.x;  // 0..127
  const int b = bt >> 5;
  const int t0 = (bt & 31) * 32;
  const int co0 = blockIdx.y * 128;
  __shared__ __align__(16) char smem[49152];
  short(*Xst)[5][40] = reinterpret_cast<short(*)[5][40]>(smem);        // [34][5][40] = 13600 B
  short(*As)[40] = reinterpret_cast<short(*)[40]>(smem + 13600);       // [128][40] = 10240 B
  float(*Ds)[96] = reinterpret_cast<float(*)[96]>(smem);               // epilogue overlay 49152 B
  const int tid = threadIdx.x;
  const int wid = tid >> 6, lane = tid & 63;
  const int wm = wid >> 1, wn = wid & 1;
  const int l15 = lane & 15, lg = lane >> 4;
  const f32x4 zf = {0.f, 0.f, 0.f, 0.f};
  f32x4 acc[4][3];
#pragma unroll
  for (int i = 0; i < 4; ++i)
#pragma unroll
    for (int j = 0; j < 3; ++j) acc[i][j] = zf;
  const int aco = tid >> 1, ahf = (tid & 1) * 16;
  int ctl[3], cw[3];
#pragma unroll
  for (int sn = 0; sn < 3; ++sn) {
    int c = wn * 48 + sn * 16 + l15;
    ctl[sn] = c / 3;
    cw[sn] = c - ctl[sn] * 3;
  }
  for (int cc = 0; cc < 16; ++cc) {
    const int ci0 = cc * 32;
    __syncthreads();
    for (int i = tid; i < 34 * 32; i += 256) {
      const int trow = i >> 5, ci = i & 31;
      const int tg = t0 - 1 + trow;
      short v0 = 0, v1 = 0, v2 = 0, v3 = 0, v4 = 0;
      if (tg >= 0 && tg < 1024) {
        const short* src = &h1[((size_t)(b * 512 + ci0 + ci) * 1024 + tg) * 5];
        v0 = src[0]; v1 = src[1]; v2 = src[2]; v3 = src[3]; v4 = src[4];
      }
      short* d = &Xst[trow][0][ci];
      d[0] = v0; d[40] = v1; d[80] = v2; d[120] = v3; d[160] = v4;
    }
    for (int p = 0; p < 9; ++p) {
      __syncthreads();
      {
        const int4* s = reinterpret_cast<const int4*>(
            &wt2[((co0 + aco) * 9 + p) * 512 + ci0 + ahf]);
        int4* d = reinterpret_cast<int4*>(&As[aco][ahf]);
        d[0] = s[0];
        d[1] = s[1];
      }
      __syncthreads();
      const int dt = p / 3, dw = p - dt * 3;
      bf16x8 bfr[3];
#pragma unroll
      for (int sn = 0; sn < 3; ++sn)
        bfr[sn] = *reinterpret_cast<const bf16x8*>(&Xst[ctl[sn] + dt][cw[sn] + dw][lg * 8]);
#pragma unroll
      for (int sm = 0; sm < 4; ++sm) {
        bf16x8 a = *reinterpret_cast<const bf16x8*>(&As[wm * 64 + sm * 16 + l15][lg * 8]);
#pragma unroll
        for (int sn = 0; sn < 3; ++sn)
          acc[sm][sn] = __builtin_amdgcn_mfma_f32_16x16x32_bf16(a, bfr[sn], acc[sm][sn], 0, 0, 0);
      }
    }
  }
  __syncthreads();
#pragma unroll
  for (int sm = 0; sm < 4; ++sm)
#pragma unroll
    for (int sn = 0; sn < 3; ++sn)
#pragma unroll
      for (int r = 0; r < 4; ++r)
        Ds[wm * 64 + sm * 16 + lg * 4 + r][wn * 48 + sn * 16 + l15] = acc[sm][sn][r];
  __syncthreads();
  for (int e = tid; e < 4096; e += 256) {
    const int co = e & 127, tt = e >> 7;
    float m = fmaxf(fmaxf(Ds[co][tt * 3], Ds[co][tt * 3 + 1]), Ds[co][tt * 3 + 2]) + bias[co0 + co];
    emb_in[((size_t)(b * 1024) + t0 + tt) * 512 + co0 + co] = fmaxf(m, 0.f);
  }
}

// ---------------------------------------------------------------------------
// LayerNorm kernels. wave-per-row (512 cols, 8 per lane).
// ---------------------------------------------------------------------------
__global__ __launch_bounds__(256) void ln_double_kernel(
    const float* __restrict__ x, const float* __restrict__ g0,
    const float* __restrict__ b0, const float* __restrict__ g1,
    const float* __restrict__ b1, float* __restrict__ o0, float* __restrict__ o1) {
  const int row = blockIdx.x * 4 + (threadIdx.x >> 6);
  const int lane = threadIdx.x & 63;
  const float* xr = x + (size_t)row * 512;
  float v[8];
#pragma unroll
  for (int j = 0; j < 8; ++j) v[j] = xr[j * 64 + lane];
  float s = 0;
#pragma unroll
  for (int j = 0; j < 8; ++j) s += v[j];
  s = wave_sum(s);
  const float mean = s * (1.f / 512.f);
  float q = 0;
#pragma unroll
  for (int j = 0; j < 8; ++j) { float d = v[j] - mean; q += d * d; }
  q = wave_sum(q);
  const float rs = rsqrtf(q * (1.f / 512.f) + 1e-5f);
#pragma unroll
  for (int j = 0; j < 8; ++j) {
    const int ci = j * 64 + lane;
    float e = (v[j] - mean) * rs * g0[ci] + b0[ci];
    o0[(size_t)row * 512 + ci] = e;
    v[j] = e;
  }
  s = 0;
#pragma unroll
  for (int j = 0; j < 8; ++j) s += v[j];
  s = wave_sum(s);
  const float mean2 = s * (1.f / 512.f);
  q = 0;
#pragma unroll
  for (int j = 0; j < 8; ++j) { float d = v[j] - mean2; q += d * d; }
  q = wave_sum(q);
  const float rs2 = rsqrtf(q * (1.f / 512.f) + 1e-5f);
#pragma unroll
  for (int j = 0; j < 8; ++j) {
    const int ci = j * 64 + lane;
    o1[(size_t)row * 512 + ci] = (v[j] - mean2) * rs2 * g1[ci] + b1[ci];
  }
}

__global__ __launch_bounds__(256) void ln_kernel(
    const float* __restrict__ x, const float* __restrict__ g,
    const float* __restrict__ b, float* __restrict__ o) {
  const int row = blockIdx.x * 4 + (threadIdx.x >> 6);
  const int lane = threadIdx.x & 63;
  const float* xr = x + (size_t)row * 512;
  float v[8];
#pragma unroll
  for (int j = 0; j < 8; ++j) v[j] = xr[j * 64 + lane];
  float s = 0;
#pragma unroll
  for (int j = 0; j < 8; ++j) s += v[j];
  s = wave_sum(s);
  const float mean = s * (1.f / 512.f);
  float q = 0;
#pragma unroll
  for (int j = 0; j < 8; ++j) { float d = v[j] - mean; q += d * d; }
  q = wave_sum(q);
  const float rs = rsqrtf(q * (1.f / 512.f) + 1e-5f);
#pragma unroll
  for (int j = 0; j < 8; ++j) {
    const int ci = j * 64 + lane;
    o[(size_t)row * 512 + ci] = (v[j] - mean) * rs * g[ci] + b[ci];
  }
}

// ---------------------------------------------------------------------------
// 1D neighborhood attention (K=7) with rpb. q,k,v fp32 [b][t][h*64+d]
// (q pre-scaled by 1/8 in its GEMM). wave per (b,h,t); lane = d.
// ---------------------------------------------------------------------------
__global__ __launch_bounds__(256) void na1d_kernel(
    const float* __restrict__ q, const float* __restrict__ k,
    const float* __restrict__ v, const float* __restrict__ rpb,
    float* __restrict__ ctx) {
  const int W = blockIdx.x * 4 + (threadIdx.x >> 6);
  const int lane = threadIdx.x & 63;
  const int b = W >> 13, h = (W >> 10) & 7, t = W & 1023;
  int ni = t - 3;
  ni = ni < 0 ? 0 : (ni > 1017 ? 1017 : ni);
  const size_t base = (size_t)(b * 1024) * 512 + h * 64;
  const float qv = q[base + (size_t)t * 512 + lane];
  const float* kb = k + base + (size_t)ni * 512;
  float s[7];
#pragma unroll
  for (int j = 0; j < 7; ++j) {
    float pd = qv * kb[j * 512 + lane];
    pd = wave_sum(pd);
    s[j] = pd + rpb[h * 13 + (ni + j - t + 6)];
  }
  float mx = s[0];
#pragma unroll
  for (int j = 1; j < 7; ++j) mx = fmaxf(mx, s[j]);
  float den = 0;
#pragma unroll
  for (int j = 0; j < 7; ++j) { s[j] = expf(s[j] - mx); den += s[j]; }
  const float inv = 1.f / den;
  const float* vb = v + base + (size_t)ni * 512;
  float o = 0;
#pragma unroll
  for (int j = 0; j < 7; ++j) o += s[j] * vb[j * 512 + lane];
  ctx[base + (size_t)t * 512 + lane] = o * inv;
}

// ---------------------------------------------------------------------------
// Transformer GEMM: C[M=4096][N] = A[M][K] (fp32) x Wt[N][K] (bf16) + bias,
// EPI: 0 = bias, 1 = bias then *0.125 (q), 2 = bias+gelu, 3 = bias+residual.
// Tile 128x64, 4 waves 2x2, BK=32.
// ---------------------------------------------------------------------------
template <int EPI>
__global__ __launch_bounds__(256) void gemm_tf(
    const float* __restrict__ A, const short* __restrict__ Wt,
    const float* __restrict__ bias, const float* __restrict__ res,
    float* __restrict__ C, int K, int N) {
  const int m0 = blockIdx.x * 128, n0 = blockIdx.y * 64;
  __shared__ short Asm[128][40];
  __shared__ short Bsm[64][40];
  const int tid = threadIdx.x;
  const int wid = tid >> 6, lane = tid & 63;
  const int wm = wid >> 1, wn = wid & 1;
  const int l15 = lane & 15, lg = lane >> 4;
  const f32x4 zf = {0.f, 0.f, 0.f, 0.f};
  f32x4 acc[4][2];
#pragma unroll
  for (int i = 0; i < 4; ++i) { acc[i][0] = zf; acc[i][1] = zf; }
  const int ar = tid >> 1, ahf = (tid & 1) * 16;
  for (int k0 = 0; k0 < K; k0 += 32) {
    __syncthreads();
    {
      const float4* s = reinterpret_cast<const float4*>(&A[(size_t)(m0 + ar) * K + k0 + ahf]);
      float4 f0 = s[0], f1 = s[1], f2 = s[2], f3 = s[3];
      short* d = &Asm[ar][ahf];
      d[0] = f2bf(f0.x);  d[1] = f2bf(f0.y);  d[2] = f2bf(f0.z);  d[3] = f2bf(f0.w);
      d[4] = f2bf(f1.x);  d[5] = f2bf(f1.y);  d[6] = f2bf(f1.z);  d[7] = f2bf(f1.w);
      d[8] = f2bf(f2.x);  d[9] = f2bf(f2.y);  d[10] = f2bf(f2.z); d[11] = f2bf(f2.w);
      d[12] = f2bf(f3.x); d[13] = f2bf(f3.y); d[14] = f2bf(f3.z); d[15] = f2bf(f3.w);
    }
    if (tid < 128) {
      const int br = tid >> 1, bhf = (tid & 1) * 16;
      const int4* s = reinterpret_cast<const int4*>(&Wt[(size_t)(n0 + br) * K + k0 + bhf]);
      int4* d = reinterpret_cast<int4*>(&Bsm[br][bhf]);
      d[0] = s[0];
      d[1] = s[1];
    }
    __syncthreads();
    bf16x8 bfr[2];
#pragma unroll
    for (int sn = 0; sn < 2; ++sn)
      bfr[sn] = *reinterpret_cast<const bf16x8*>(&Bsm[wn * 32 + sn * 16 + l15][lg * 8]);
#pragma unroll
    for (int sm = 0; sm < 4; ++sm) {
      bf16x8 a = *reinterpret_cast<const bf16x8*>(&Asm[wm * 64 + sm * 16 + l15][lg * 8]);
#pragma unroll
      for (int sn = 0; sn < 2; ++sn)
        acc[sm][sn] = __builtin_amdgcn_mfma_f32_16x16x32_bf16(a, bfr[sn], acc[sm][sn], 0, 0, 0);
    }
  }
#pragma unroll
  for (int sm = 0; sm < 4; ++sm)
#pragma unroll
    for (int sn = 0; sn < 2; ++sn)
#pragma unroll
      for (int r = 0; r < 4; ++r) {
        const int m = m0 + wm * 64 + sm * 16 + lg * 4 + r;
        const int n = n0 + wn * 32 + sn * 16 + l15;
        float val = acc[sm][sn][r] + bias[n];
        if (EPI == 1) val *= 0.125f;
        if (EPI == 2) val = 0.5f * val * (1.f + erff(val * 0.70710678f));
        if (EPI == 3) val += res[(size_t)m * N + n];
        C[(size_t)m * N + n] = val;
      }
}

// ---------------------------------------------------------------------------
extern "C" void kernel_launch(void* const* d_in, const int* in_sizes, int n_in,
                              void* d_out, int out_size, void* d_ws, size_t ws_size,
                              hipStream_t stream) {
  (void)in_sizes; (void)n_in; (void)out_size;
  const float* x        = (const float*)d_in[0];
  const float* conv0_w  = (const float*)d_in[1];
  const float* conv0_b  = (const float*)d_in[2];
  const float* conv1_w  = (const float*)d_in[3];
  const float* conv1_b  = (const float*)d_in[4];
  const float* conv2_w  = (const float*)d_in[5];
  const float* conv2_b  = (const float*)d_in[6];
  const float* emb_ln_g = (const float*)d_in[7];
  const float* emb_ln_b = (const float*)d_in[8];
  const float* q_w  = (const float*)d_in[9];
  const float* q_b  = (const float*)d_in[10];
  const float* k_w  = (const float*)d_in[11];
  const float* k_b  = (const float*)d_in[12];
  const float* v_w  = (const float*)d_in[13];
  const float* v_b  = (const float*)d_in[14];
  const float* rpb  = (const float*)d_in[15];
  const float* ao_w = (const float*)d_in[16];
  const float* ao_b = (const float*)d_in[17];
  const float* ln1_g = (const float*)d_in[18];
  const float* ln1_b = (const float*)d_in[19];
  const float* ln2_g = (const float*)d_in[20];
  const float* ln2_b = (const float*)d_in[21];
  const float* m1_w = (const float*)d_in[22];
  const float* m1_b = (const float*)d_in[23];
  const float* m2_w = (const float*)d_in[24];
  const float* m2_b = (const float*)d_in[25];

  char* ws = (char*)d_ws;
  size_t off = 0;
  auto alloc = [&](size_t bytes) -> char* {
    char* p = ws + off;
    off += (bytes + 255) & ~(size_t)255;
    return p;
  };
  short* h0   = (short*)alloc(4ull * 256 * 1024 * 26 * 2);   // 54.5 MB
  short* h1   = (short*)alloc(4ull * 512 * 1024 * 5 * 2);    // 21 MB
  float* embi = (float*)alloc(4ull * 1024 * 512 * 4);
  float* emb  = (float*)alloc(4ull * 1024 * 512 * 4);
  float* hs1  = (float*)alloc(4ull * 1024 * 512 * 4);
  float* qb   = (float*)alloc(4ull * 1024 * 512 * 4);
  float* kb   = (float*)alloc(4ull * 1024 * 512 * 4);
  float* vb   = (float*)alloc(4ull * 1024 * 512 * 4);
  float* ctx  = (float*)alloc(4ull * 1024 * 512 * 4);
  float* hs   = (float*)alloc(4ull * 1024 * 512 * 4);
  short* wt1  = (short*)alloc(512ull * 12 * 256 * 2);
  short* wt2  = (short*)alloc(512ull * 9 * 512 * 2);
  short* wtq  = (short*)alloc(512ull * 512 * 2);
  short* wtk  = (short*)alloc(512ull * 512 * 2);
  short* wtv  = (short*)alloc(512ull * 512 * 2);
  short* wtao = (short*)alloc(512ull * 512 * 2);
  short* wtm1 = (short*)alloc(2048ull * 512 * 2);
  short* wtm2 = (short*)alloc(512ull * 2048 * 2);
  if (ws_size < off) return;  // fail visibly (poisoned output) instead of OOB
  float* mid  = (float*)h0;   // reuse: 33.5 MB <= 54.5 MB, h0 dead after conv1
  float* ln2o = embi;         // reuse: embi dead after ln_double
  float* outp = (float*)d_out;

  prep_w1<<<512, 256, 0, stream>>>(conv1_w, wt1);
  prep_w2<<<512, 256, 0, stream>>>(conv2_w, wt2);
  dim3 tb(32, 8);
  prep_wt<<<dim3(16, 16), tb, 0, stream>>>(q_w, wtq, 512, 512);
  prep_wt<<<dim3(16, 16), tb, 0, stream>>>(k_w, wtk, 512, 512);
  prep_wt<<<dim3(16, 16), tb, 0, stream>>>(v_w, wtv, 512, 512);
  prep_wt<<<dim3(16, 16), tb, 0, stream>>>(ao_w, wtao, 512, 512);
  prep_wt<<<dim3(16, 64), tb, 0, stream>>>(m1_w, wtm1, 512, 2048);
  prep_wt<<<dim3(64, 16), tb, 0, stream>>>(m2_w, wtm2, 2048, 512);

  conv0_kernel<<<4096, 256, 0, stream>>>(x, conv0_w, conv0_b, h0);
  conv1_kernel<<<dim3(512, 4), 256, 0, stream>>>(h0, wt1, conv1_b, h1);
  conv2_kernel<<<dim3(128, 4), 256, 0, stream>>>(h1, wt2, conv2_b, embi);
  ln_double_kernel<<<1024, 256, 0, stream>>>(embi, emb_ln_g, emb_ln_b, ln1_g, ln1_b, emb, hs1);
  gemm_tf<1><<<dim3(32, 8), 256, 0, stream>>>(hs1, wtq, q_b, nullptr, qb, 512, 512);
  gemm_tf<0><<<dim3(32, 8), 256, 0, stream>>>(hs1, wtk, k_b, nullptr, kb, 512, 512);
  gemm_tf<0><<<dim3(32, 8), 256, 0, stream>>>(hs1, wtv, v_b, nullptr, vb, 512, 512);
  na1d_kernel<<<8192, 256, 0, stream>>>(qb, kb, vb, rpb, ctx);
  gemm_tf<3><<<dim3(32, 8), 256, 0, stream>>>(ctx, wtao, ao_b, emb, hs, 512, 512);
  ln_kernel<<<1024, 256, 0, stream>>>(hs, ln2_g, ln2_b, ln2o);
  gemm_tf<2><<<dim3(32, 32), 256, 0, stream>>>(ln2o, wtm1, m1_b, nullptr, mid, 512, 2048);
  gemm_tf<3><<<dim3(32, 8), 256, 0, stream>>>(mid, wtm2, m2_b, hs, outp, 2048, 512);
}

// Round 2
// 627.234 us; speedup vs baseline: 1.1655x; 1.1655x over previous
//
#include <hip/hip_runtime.h>
#include <hip/hip_bf16.h>
#include <math.h>

// ---------------------------------------------------------------------------
// Model constants
//   B=4, T=1024, F_IN=80, C0=256, C_EMB=512, HEADS=8, K=7, D_HEAD=64, MLP=2048
// ---------------------------------------------------------------------------

typedef __bf16 bf16x8 __attribute__((ext_vector_type(8)));
typedef float f32x4 __attribute__((ext_vector_type(4)));

static __device__ __forceinline__ short f2bf(float f) {
  __hip_bfloat16 h = __float2bfloat16(f);
  return __builtin_bit_cast(short, h);
}

static __device__ __forceinline__ float wave_sum(float v) {
#pragma unroll
  for (int o = 32; o; o >>= 1) v += __shfl_xor(v, o);
  return v;
}

// ---------------------------------------------------------------------------
// conv0 (1->256, 3x3, pad t +-1) + maxpool3(w) + relu.  x:[4,1,1024,80] fp32
// out h0 bf16 [4][1024][26][256]   (ci-contiguous for conv1 staging)
// block = (b,t), 256 threads = one per output channel
// ---------------------------------------------------------------------------
__global__ __launch_bounds__(256) void conv0_kernel(
    const float* __restrict__ x, const float* __restrict__ w,
    const float* __restrict__ bias, short* __restrict__ h0) {
  const int b = blockIdx.x >> 10;
  const int t = blockIdx.x & 1023;
  const int c = threadIdx.x;
  __shared__ float xs[3][80];
  for (int i = threadIdx.x; i < 240; i += 256) {
    int dt = i / 80, f = i - dt * 80;
    int tt = t + dt - 1;
    xs[dt][f] = (tt >= 0 && tt < 1024) ? x[(b * 1024 + tt) * 80 + f] : 0.f;
  }
  float wr[9];
#pragma unroll
  for (int i = 0; i < 9; ++i) wr[i] = w[c * 9 + i];
  const float bi = bias[c];
  __syncthreads();
  short* out = &h0[((size_t)(b * 1024 + t) * 26) * 256 + c];
  for (int fo = 0; fo < 26; ++fo) {
    float m = -1e30f;
#pragma unroll
    for (int p = 0; p < 3; ++p) {
      const int f = fo * 3 + p;
      float acc = bi;
#pragma unroll
      for (int dt = 0; dt < 3; ++dt)
#pragma unroll
        for (int df = 0; df < 3; ++df)
          acc += xs[dt][f + df] * wr[dt * 3 + df];
      m = fmaxf(m, acc);
    }
    out[fo * 256] = f2bf(fmaxf(m, 0.f));
  }
}

// ---------------------------------------------------------------------------
// Weight pre-transposes (fp32 -> bf16, once per launch)
// ---------------------------------------------------------------------------
// conv1_w [512][256][1][12] -> wt1 [co][kw][ci] bf16
__global__ __launch_bounds__(256) void prep_w1(const float* __restrict__ w,
                                               short* __restrict__ wt) {
  const int co = blockIdx.x;
  __shared__ float ls[3072];
  for (int i = threadIdx.x; i < 3072; i += 256) ls[i] = w[co * 3072 + i];
  __syncthreads();
  for (int i = threadIdx.x; i < 3072; i += 256) {
    int kw = i >> 8, ci = i & 255;
    wt[co * 3072 + i] = f2bf(ls[ci * 12 + kw]);
  }
}

// conv2_w [512][512][3][3] -> wt2 [co][p=dt*3+dw][ci] bf16
__global__ __launch_bounds__(256) void prep_w2(const float* __restrict__ w,
                                               short* __restrict__ wt) {
  const int co = blockIdx.x;
  __shared__ float ls[4608];
  for (int i = threadIdx.x; i < 4608; i += 256) ls[i] = w[co * 4608 + i];
  __syncthreads();
  for (int i = threadIdx.x; i < 4608; i += 256) {
    int p = i >> 9, ci = i & 511;
    wt[co * 4608 + i] = f2bf(ls[ci * 9 + p]);
  }
}

// dense W [K][N] fp32 -> Wt [N][K] bf16 (tiled transpose)
__global__ void prep_wt(const float* __restrict__ w, short* __restrict__ wt,
                        int K, int N) {
  __shared__ float tile[32][33];
  const int k0 = blockIdx.x * 32, n0 = blockIdx.y * 32;
  const int tx = threadIdx.x, ty = threadIdx.y;
  for (int r = ty; r < 32; r += 8) tile[r][tx] = w[(size_t)(k0 + r) * N + n0 + tx];
  __syncthreads();
  for (int r = ty; r < 32; r += 8) wt[(size_t)(n0 + r) * K + k0 + tx] = f2bf(tile[tx][r]);
}

// ---------------------------------------------------------------------------
// conv1 (256->512, 1x12) + pool3 + relu via MFMA GEMM.
// h0 bf16 [4][1024][26][256] -> h1 bf16 [4][512][1024][5]
// Block: co_tile=128, t_tile=32 (N = 32t x 16w slots). 8 waves, grid 2x4,
// wave tile 64co x 128col. K-loop: 8 ci-chunks of 32; per chunk ALL 12 kw of
// the weights staged at once -> 2 barriers per chunk (16 total).
// All LDS traffic is b128, conflict-free (rows are 64B, starts spread).
// ---------------------------------------------------------------------------
__global__ __launch_bounds__(512, 2) void conv1_kernel(
    const short* __restrict__ h0, const short* __restrict__ wt1,
    const float* __restrict__ bias, short* __restrict__ h1) {
  const int b = blockIdx.x >> 5;
  const int t0 = (blockIdx.x & 31) * 32;
  const int co0 = blockIdx.y * 128;
  __shared__ short XsF[26688];          // rows t*26+w (834 rows x 32ci), 53.4 KB
  __shared__ short AsF[12 * 128 * 32];  // [kw][co][ci], 98.3 KB
  const int tid = threadIdx.x;
  const int lane = tid & 63;
  const int wid = tid >> 6;   // 0..7
  const int wm = wid >> 2;    // 0..1  (64 co each)
  const int wn = wid & 3;     // 0..3  (128 cols = 8 t each)
  const int l15 = lane & 15, lg = lane >> 4;

  const f32x4 zf = {0.f, 0.f, 0.f, 0.f};
  f32x4 acc[4][8];
#pragma unroll
  for (int i = 0; i < 4; ++i)
#pragma unroll
    for (int j = 0; j < 8; ++j) acc[i][j] = zf;

  for (int cc = 0; cc < 8; ++cc) {
    const int ci0 = cc * 32;
    __syncthreads();  // previous chunk's LDS reads complete
    // X stage: 32t x 26w x 32ci = 3328 b128 units, LDS-linear
    for (int u = tid; u < 3328; u += 512) {
      const int t = u / 104;
      const int rem = u - t * 104;
      const int w = rem >> 2, q = rem & 3;
      const int4 v = *reinterpret_cast<const int4*>(
          &h0[((size_t)(b * 1024 + t0 + t) * 26 + w) * 256 + ci0 + q * 8]);
      *reinterpret_cast<int4*>(&XsF[u * 8]) = v;
    }
    // A stage: 12kw x 128co x 32ci = 6144 b128 units, LDS-linear
    for (int u = tid; u < 6144; u += 512) {
      const int kw = u >> 9, co = (u >> 2) & 127, q = u & 3;
      const int4 v = *reinterpret_cast<const int4*>(
          &wt1[((size_t)(co0 + co) * 12 + kw) * 256 + ci0 + q * 8]);
      *reinterpret_cast<int4*>(&AsF[u * 8]) = v;
    }
    __syncthreads();  // staged data visible
    for (int kw = 0; kw < 12; ++kw) {
      bf16x8 a[4];
#pragma unroll
      for (int sm = 0; sm < 4; ++sm)
        a[sm] = *reinterpret_cast<const bf16x8*>(
            &AsF[(kw * 128 + wm * 64 + sm * 16 + l15) * 32 + lg * 8]);
#pragma unroll
      for (int sn = 0; sn < 8; ++sn) {
        const int t = wn * 8 + sn;
        bf16x8 bf = *reinterpret_cast<const bf16x8*>(
            &XsF[(t * 26 + l15 + kw) * 32 + lg * 8]);
#pragma unroll
        for (int sm = 0; sm < 4; ++sm)
          acc[sm][sn] = __builtin_amdgcn_mfma_f32_16x16x32_bf16(a[sm], bf, acc[sm][sn], 0, 0, 0);
      }
    }
  }
  // epilogue: pool w-triples (within 16-lane groups) + bias + relu
  const int basel = lane & 48;
  const int wsrc = (l15 < 5) ? 3 * l15 : 0;
#pragma unroll
  for (int sm = 0; sm < 4; ++sm)
#pragma unroll
    for (int sn = 0; sn < 8; ++sn) {
      const int t = t0 + wn * 8 + sn;
#pragma unroll
      for (int r = 0; r < 4; ++r) {
        float val = acc[sm][sn][r];
        float v0 = __shfl(val, basel + wsrc);
        float v1 = __shfl(val, basel + wsrc + 1);
        float v2 = __shfl(val, basel + wsrc + 2);
        if (l15 < 5) {
          const int co = co0 + wm * 64 + sm * 16 + lg * 4 + r;
          float p = fmaxf(fmaxf(v0, v1), v2) + bias[co];
          h1[((size_t)(b * 512 + co) * 1024 + t) * 5 + l15] = f2bf(fmaxf(p, 0.f));
        }
      }
    }
}

// ---------------------------------------------------------------------------
// conv2 (512->512, 3x3, pad t +-1) + pool3 + relu via MFMA GEMM, output
// transposed: emb_in fp32 [b][t][512].
// Block: co_tile=128, t_tile=32 (96 packed cols = t*3+w). 4 waves 2x2.
// ---------------------------------------------------------------------------
__global__ __launch_bounds__(256) void conv2_kernel(
    const short* __restrict__ h1, const short* __restrict__ wt2,
    const float* __restrict__ bias, float* __restrict__ emb_in) {
  const int bt = blockIdx.x;  // 0..127
  const int b = bt >> 5;
  const int t0 = (bt & 31) * 32;
  const int co0 = blockIdx.y * 128;
  __shared__ __align__(16) char smem[49152];
  short(*Xst)[5][40] = reinterpret_cast<short(*)[5][40]>(smem);        // [34][5][40] = 13600 B
  short(*As)[40] = reinterpret_cast<short(*)[40]>(smem + 13600);       // [128][40] = 10240 B
  float(*Ds)[96] = reinterpret_cast<float(*)[96]>(smem);               // epilogue overlay 49152 B
  const int tid = threadIdx.x;
  const int wid = tid >> 6, lane = tid & 63;
  const int wm = wid >> 1, wn = wid & 1;
  const int l15 = lane & 15, lg = lane >> 4;
  const f32x4 zf = {0.f, 0.f, 0.f, 0.f};
  f32x4 acc[4][3];
#pragma unroll
  for (int i = 0; i < 4; ++i)
#pragma unroll
    for (int j = 0; j < 3; ++j) acc[i][j] = zf;
  const int aco = tid >> 1, ahf = (tid & 1) * 16;
  int ctl[3], cw[3];
#pragma unroll
  for (int sn = 0; sn < 3; ++sn) {
    int c = wn * 48 + sn * 16 + l15;
    ctl[sn] = c / 3;
    cw[sn] = c - ctl[sn] * 3;
  }
  for (int cc = 0; cc < 16; ++cc) {
    const int ci0 = cc * 32;
    __syncthreads();
    for (int i = tid; i < 34 * 32; i += 256) {
      const int trow = i >> 5, ci = i & 31;
      const int tg = t0 - 1 + trow;
      short v0 = 0, v1 = 0, v2 = 0, v3 = 0, v4 = 0;
      if (tg >= 0 && tg < 1024) {
        const short* src = &h1[((size_t)(b * 512 + ci0 + ci) * 1024 + tg) * 5];
        v0 = src[0]; v1 = src[1]; v2 = src[2]; v3 = src[3]; v4 = src[4];
      }
      short* d = &Xst[trow][0][ci];
      d[0] = v0; d[40] = v1; d[80] = v2; d[120] = v3; d[160] = v4;
    }
    for (int p = 0; p < 9; ++p) {
      __syncthreads();
      {
        const int4* s = reinterpret_cast<const int4*>(
            &wt2[((co0 + aco) * 9 + p) * 512 + ci0 + ahf]);
        int4* d = reinterpret_cast<int4*>(&As[aco][ahf]);
        d[0] = s[0];
        d[1] = s[1];
      }
      __syncthreads();
      const int dt = p / 3, dw = p - dt * 3;
      bf16x8 bfr[3];
#pragma unroll
      for (int sn = 0; sn < 3; ++sn)
        bfr[sn] = *reinterpret_cast<const bf16x8*>(&Xst[ctl[sn] + dt][cw[sn] + dw][lg * 8]);
#pragma unroll
      for (int sm = 0; sm < 4; ++sm) {
        bf16x8 a = *reinterpret_cast<const bf16x8*>(&As[wm * 64 + sm * 16 + l15][lg * 8]);
#pragma unroll
        for (int sn = 0; sn < 3; ++sn)
          acc[sm][sn] = __builtin_amdgcn_mfma_f32_16x16x32_bf16(a, bfr[sn], acc[sm][sn], 0, 0, 0);
      }
    }
  }
  __syncthreads();
#pragma unroll
  for (int sm = 0; sm < 4; ++sm)
#pragma unroll
    for (int sn = 0; sn < 3; ++sn)
#pragma unroll
      for (int r = 0; r < 4; ++r)
        Ds[wm * 64 + sm * 16 + lg * 4 + r][wn * 48 + sn * 16 + l15] = acc[sm][sn][r];
  __syncthreads();
  for (int e = tid; e < 4096; e += 256) {
    const int co = e & 127, tt = e >> 7;
    float m = fmaxf(fmaxf(Ds[co][tt * 3], Ds[co][tt * 3 + 1]), Ds[co][tt * 3 + 2]) + bias[co0 + co];
    emb_in[((size_t)(b * 1024) + t0 + tt) * 512 + co0 + co] = fmaxf(m, 0.f);
  }
}

// ---------------------------------------------------------------------------
// LayerNorm kernels. wave-per-row (512 cols, 8 per lane).
// ---------------------------------------------------------------------------
__global__ __launch_bounds__(256) void ln_double_kernel(
    const float* __restrict__ x, const float* __restrict__ g0,
    const float* __restrict__ b0, const float* __restrict__ g1,
    const float* __restrict__ b1, float* __restrict__ o0, float* __restrict__ o1) {
  const int row = blockIdx.x * 4 + (threadIdx.x >> 6);
  const int lane = threadIdx.x & 63;
  const float* xr = x + (size_t)row * 512;
  float v[8];
#pragma unroll
  for (int j = 0; j < 8; ++j) v[j] = xr[j * 64 + lane];
  float s = 0;
#pragma unroll
  for (int j = 0; j < 8; ++j) s += v[j];
  s = wave_sum(s);
  const float mean = s * (1.f / 512.f);
  float q = 0;
#pragma unroll
  for (int j = 0; j < 8; ++j) { float d = v[j] - mean; q += d * d; }
  q = wave_sum(q);
  const float rs = rsqrtf(q * (1.f / 512.f) + 1e-5f);
#pragma unroll
  for (int j = 0; j < 8; ++j) {
    const int ci = j * 64 + lane;
    float e = (v[j] - mean) * rs * g0[ci] + b0[ci];
    o0[(size_t)row * 512 + ci] = e;
    v[j] = e;
  }
  s = 0;
#pragma unroll
  for (int j = 0; j < 8; ++j) s += v[j];
  s = wave_sum(s);
  const float mean2 = s * (1.f / 512.f);
  q = 0;
#pragma unroll
  for (int j = 0; j < 8; ++j) { float d = v[j] - mean2; q += d * d; }
  q = wave_sum(q);
  const float rs2 = rsqrtf(q * (1.f / 512.f) + 1e-5f);
#pragma unroll
  for (int j = 0; j < 8; ++j) {
    const int ci = j * 64 + lane;
    o1[(size_t)row * 512 + ci] = (v[j] - mean2) * rs2 * g1[ci] + b1[ci];
  }
}

__global__ __launch_bounds__(256) void ln_kernel(
    const float* __restrict__ x, const float* __restrict__ g,
    const float* __restrict__ b, float* __restrict__ o) {
  const int row = blockIdx.x * 4 + (threadIdx.x >> 6);
  const int lane = threadIdx.x & 63;
  const float* xr = x + (size_t)row * 512;
  float v[8];
#pragma unroll
  for (int j = 0; j < 8; ++j) v[j] = xr[j * 64 + lane];
  float s = 0;
#pragma unroll
  for (int j = 0; j < 8; ++j) s += v[j];
  s = wave_sum(s);
  const float mean = s * (1.f / 512.f);
  float q = 0;
#pragma unroll
  for (int j = 0; j < 8; ++j) { float d = v[j] - mean; q += d * d; }
  q = wave_sum(q);
  const float rs = rsqrtf(q * (1.f / 512.f) + 1e-5f);
#pragma unroll
  for (int j = 0; j < 8; ++j) {
    const int ci = j * 64 + lane;
    o[(size_t)row * 512 + ci] = (v[j] - mean) * rs * g[ci] + b[ci];
  }
}

// ---------------------------------------------------------------------------
// 1D neighborhood attention (K=7) with rpb. q,k,v fp32 [b][t][h*64+d]
// (q pre-scaled by 1/8 in its GEMM). wave per (b,h,t); lane = d.
// ---------------------------------------------------------------------------
__global__ __launch_bounds__(256) void na1d_kernel(
    const float* __restrict__ q, const float* __restrict__ k,
    const float* __restrict__ v, const float* __restrict__ rpb,
    float* __restrict__ ctx) {
  const int W = blockIdx.x * 4 + (threadIdx.x >> 6);
  const int lane = threadIdx.x & 63;
  const int b = W >> 13, h = (W >> 10) & 7, t = W & 1023;
  int ni = t - 3;
  ni = ni < 0 ? 0 : (ni > 1017 ? 1017 : ni);
  const size_t base = (size_t)(b * 1024) * 512 + h * 64;
  const float qv = q[base + (size_t)t * 512 + lane];
  const float* kb = k + base + (size_t)ni * 512;
  float s[7];
#pragma unroll
  for (int j = 0; j < 7; ++j) {
    float pd = qv * kb[j * 512 + lane];
    pd = wave_sum(pd);
    s[j] = pd + rpb[h * 13 + (ni + j - t + 6)];
  }
  float mx = s[0];
#pragma unroll
  for (int j = 1; j < 7; ++j) mx = fmaxf(mx, s[j]);
  float den = 0;
#pragma unroll
  for (int j = 0; j < 7; ++j) { s[j] = expf(s[j] - mx); den += s[j]; }
  const float inv = 1.f / den;
  const float* vb = v + base + (size_t)ni * 512;
  float o = 0;
#pragma unroll
  for (int j = 0; j < 7; ++j) o += s[j] * vb[j * 512 + lane];
  ctx[base + (size_t)t * 512 + lane] = o * inv;
}

// ---------------------------------------------------------------------------
// Transformer GEMM: C[M=4096][N] = A[M][K] (fp32) x Wt[N][K] (bf16) + bias,
// EPI: 0 = bias, 1 = bias then *0.125 (q), 2 = bias+gelu, 3 = bias+residual.
// Tile 128x64, 4 waves 2x2, BK=32.
// ---------------------------------------------------------------------------
template <int EPI>
__global__ __launch_bounds__(256) void gemm_tf(
    const float* __restrict__ A, const short* __restrict__ Wt,
    const float* __restrict__ bias, const float* __restrict__ res,
    float* __restrict__ C, int K, int N) {
  const int m0 = blockIdx.x * 128, n0 = blockIdx.y * 64;
  __shared__ short Asm[128][40];
  __shared__ short Bsm[64][40];
  const int tid = threadIdx.x;
  const int wid = tid >> 6, lane = tid & 63;
  const int wm = wid >> 1, wn = wid & 1;
  const int l15 = lane & 15, lg = lane >> 4;
  const f32x4 zf = {0.f, 0.f, 0.f, 0.f};
  f32x4 acc[4][2];
#pragma unroll
  for (int i = 0; i < 4; ++i) { acc[i][0] = zf; acc[i][1] = zf; }
  const int ar = tid >> 1, ahf = (tid & 1) * 16;
  for (int k0 = 0; k0 < K; k0 += 32) {
    __syncthreads();
    {
      const float4* s = reinterpret_cast<const float4*>(&A[(size_t)(m0 + ar) * K + k0 + ahf]);
      float4 f0 = s[0], f1 = s[1], f2 = s[2], f3 = s[3];
      short* d = &Asm[ar][ahf];
      d[0] = f2bf(f0.x);  d[1] = f2bf(f0.y);  d[2] = f2bf(f0.z);  d[3] = f2bf(f0.w);
      d[4] = f2bf(f1.x);  d[5] = f2bf(f1.y);  d[6] = f2bf(f1.z);  d[7] = f2bf(f1.w);
      d[8] = f2bf(f2.x);  d[9] = f2bf(f2.y);  d[10] = f2bf(f2.z); d[11] = f2bf(f2.w);
      d[12] = f2bf(f3.x); d[13] = f2bf(f3.y); d[14] = f2bf(f3.z); d[15] = f2bf(f3.w);
    }
    if (tid < 128) {
      const int br = tid >> 1, bhf = (tid & 1) * 16;
      const int4* s = reinterpret_cast<const int4*>(&Wt[(size_t)(n0 + br) * K + k0 + bhf]);
      int4* d = reinterpret_cast<int4*>(&Bsm[br][bhf]);
      d[0] = s[0];
      d[1] = s[1];
    }
    __syncthreads();
    bf16x8 bfr[2];
#pragma unroll
    for (int sn = 0; sn < 2; ++sn)
      bfr[sn] = *reinterpret_cast<const bf16x8*>(&Bsm[wn * 32 + sn * 16 + l15][lg * 8]);
#pragma unroll
    for (int sm = 0; sm < 4; ++sm) {
      bf16x8 a = *reinterpret_cast<const bf16x8*>(&Asm[wm * 64 + sm * 16 + l15][lg * 8]);
#pragma unroll
      for (int sn = 0; sn < 2; ++sn)
        acc[sm][sn] = __builtin_amdgcn_mfma_f32_16x16x32_bf16(a, bfr[sn], acc[sm][sn], 0, 0, 0);
    }
  }
#pragma unroll
  for (int sm = 0; sm < 4; ++sm)
#pragma unroll
    for (int sn = 0; sn < 2; ++sn)
#pragma unroll
      for (int r = 0; r < 4; ++r) {
        const int m = m0 + wm * 64 + sm * 16 + lg * 4 + r;
        const int n = n0 + wn * 32 + sn * 16 + l15;
        float val = acc[sm][sn][r] + bias[n];
        if (EPI == 1) val *= 0.125f;
        if (EPI == 2) val = 0.5f * val * (1.f + erff(val * 0.70710678f));
        if (EPI == 3) val += res[(size_t)m * N + n];
        C[(size_t)m * N + n] = val;
      }
}

// ---------------------------------------------------------------------------
extern "C" void kernel_launch(void* const* d_in, const int* in_sizes, int n_in,
                              void* d_out, int out_size, void* d_ws, size_t ws_size,
                              hipStream_t stream) {
  (void)in_sizes; (void)n_in; (void)out_size;
  const float* x        = (const float*)d_in[0];
  const float* conv0_w  = (const float*)d_in[1];
  const float* conv0_b  = (const float*)d_in[2];
  const float* conv1_w  = (const float*)d_in[3];
  const float* conv1_b  = (const float*)d_in[4];
  const float* conv2_w  = (const float*)d_in[5];
  const float* conv2_b  = (const float*)d_in[6];
  const float* emb_ln_g = (const float*)d_in[7];
  const float* emb_ln_b = (const float*)d_in[8];
  const float* q_w  = (const float*)d_in[9];
  const float* q_b  = (const float*)d_in[10];
  const float* k_w  = (const float*)d_in[11];
  const float* k_b  = (const float*)d_in[12];
  const float* v_w  = (const float*)d_in[13];
  const float* v_b  = (const float*)d_in[14];
  const float* rpb  = (const float*)d_in[15];
  const float* ao_w = (const float*)d_in[16];
  const float* ao_b = (const float*)d_in[17];
  const float* ln1_g = (const float*)d_in[18];
  const float* ln1_b = (const float*)d_in[19];
  const float* ln2_g = (const float*)d_in[20];
  const float* ln2_b = (const float*)d_in[21];
  const float* m1_w = (const float*)d_in[22];
  const float* m1_b = (const float*)d_in[23];
  const float* m2_w = (const float*)d_in[24];
  const float* m2_b = (const float*)d_in[25];

  char* ws = (char*)d_ws;
  size_t off = 0;
  auto alloc = [&](size_t bytes) -> char* {
    char* p = ws + off;
    off += (bytes + 255) & ~(size_t)255;
    return p;
  };
  short* h0   = (short*)alloc(4ull * 256 * 1024 * 26 * 2);   // 54.5 MB
  short* h1   = (short*)alloc(4ull * 512 * 1024 * 5 * 2);    // 21 MB
  float* embi = (float*)alloc(4ull * 1024 * 512 * 4);
  float* emb  = (float*)alloc(4ull * 1024 * 512 * 4);
  float* hs1  = (float*)alloc(4ull * 1024 * 512 * 4);
  float* qb   = (float*)alloc(4ull * 1024 * 512 * 4);
  float* kb   = (float*)alloc(4ull * 1024 * 512 * 4);
  float* vb   = (float*)alloc(4ull * 1024 * 512 * 4);
  float* ctx  = (float*)alloc(4ull * 1024 * 512 * 4);
  float* hs   = (float*)alloc(4ull * 1024 * 512 * 4);
  short* wt1  = (short*)alloc(512ull * 12 * 256 * 2);
  short* wt2  = (short*)alloc(512ull * 9 * 512 * 2);
  short* wtq  = (short*)alloc(512ull * 512 * 2);
  short* wtk  = (short*)alloc(512ull * 512 * 2);
  short* wtv  = (short*)alloc(512ull * 512 * 2);
  short* wtao = (short*)alloc(512ull * 512 * 2);
  short* wtm1 = (short*)alloc(2048ull * 512 * 2);
  short* wtm2 = (short*)alloc(512ull * 2048 * 2);
  if (ws_size < off) return;  // fail visibly (poisoned output) instead of OOB
  float* mid  = (float*)h0;   // reuse: 33.5 MB <= 54.5 MB, h0 dead after conv1
  float* ln2o = embi;         // reuse: embi dead after ln_double
  float* outp = (float*)d_out;

  prep_w1<<<512, 256, 0, stream>>>(conv1_w, wt1);
  prep_w2<<<512, 256, 0, stream>>>(conv2_w, wt2);
  dim3 tb(32, 8);
  prep_wt<<<dim3(16, 16), tb, 0, stream>>>(q_w, wtq, 512, 512);
  prep_wt<<<dim3(16, 16), tb, 0, stream>>>(k_w, wtk, 512, 512);
  prep_wt<<<dim3(16, 16), tb, 0, stream>>>(v_w, wtv, 512, 512);
  prep_wt<<<dim3(16, 16), tb, 0, stream>>>(ao_w, wtao, 512, 512);
  prep_wt<<<dim3(16, 64), tb, 0, stream>>>(m1_w, wtm1, 512, 2048);
  prep_wt<<<dim3(64, 16), tb, 0, stream>>>(m2_w, wtm2, 2048, 512);

  conv0_kernel<<<4096, 256, 0, stream>>>(x, conv0_w, conv0_b, h0);
  conv1_kernel<<<dim3(128, 4), 512, 0, stream>>>(h0, wt1, conv1_b, h1);
  conv2_kernel<<<dim3(128, 4), 256, 0, stream>>>(h1, wt2, conv2_b, embi);
  ln_double_kernel<<<1024, 256, 0, stream>>>(embi, emb_ln_g, emb_ln_b, ln1_g, ln1_b, emb, hs1);
  gemm_tf<1><<<dim3(32, 8), 256, 0, stream>>>(hs1, wtq, q_b, nullptr, qb, 512, 512);
  gemm_tf<0><<<dim3(32, 8), 256, 0, stream>>>(hs1, wtk, k_b, nullptr, kb, 512, 512);
  gemm_tf<0><<<dim3(32, 8), 256, 0, stream>>>(hs1, wtv, v_b, nullptr, vb, 512, 512);
  na1d_kernel<<<8192, 256, 0, stream>>>(qb, kb, vb, rpb, ctx);
  gemm_tf<3><<<dim3(32, 8), 256, 0, stream>>>(ctx, wtao, ao_b, emb, hs, 512, 512);
  ln_kernel<<<1024, 256, 0, stream>>>(hs, ln2_g, ln2_b, ln2o);
  gemm_tf<2><<<dim3(32, 32), 256, 0, stream>>>(ln2o, wtm1, m1_b, nullptr, mid, 512, 2048);
  gemm_tf<3><<<dim3(32, 8), 256, 0, stream>>>(mid, wtm2, m2_b, hs, outp, 2048, 512);
}

// Round 3
// 506.993 us; speedup vs baseline: 1.4419x; 1.2372x over previous
//
#include <hip/hip_runtime.h>
#include <hip/hip_bf16.h>
#include <math.h>

// ---------------------------------------------------------------------------
// Model constants
//   B=4, T=1024, F_IN=80, C0=256, C_EMB=512, HEADS=8, K=7, D_HEAD=64, MLP=2048
// ---------------------------------------------------------------------------

typedef __bf16 bf16x8 __attribute__((ext_vector_type(8)));
typedef float f32x4 __attribute__((ext_vector_type(4)));

static __device__ __forceinline__ short f2bf(float f) {
  __hip_bfloat16 h = __float2bfloat16(f);
  return __builtin_bit_cast(short, h);
}

static __device__ __forceinline__ float wave_sum(float v) {
#pragma unroll
  for (int o = 32; o; o >>= 1) v += __shfl_xor(v, o);
  return v;
}

// async global->LDS, 16B per lane; dest = lds_base (wave-uniform) + lane*16
static __device__ __forceinline__ void gld16(const void* g, void* l) {
  __builtin_amdgcn_global_load_lds(
      (const __attribute__((address_space(1))) unsigned int*)g,
      (__attribute__((address_space(3))) unsigned int*)l, 16, 0, 0);
}

// ---------------------------------------------------------------------------
// conv0 (1->256, 3x3, pad t +-1) + maxpool3(w) + relu.  x:[4,1,1024,80] fp32
// out h0 bf16 [b][cc8][t1024][w26][unit4^swz][8]  (chunk-contiguous + swizzled
// 16B units so conv1 can global_load_lds linearly and read conflict-free)
// ---------------------------------------------------------------------------
__global__ __launch_bounds__(256) void conv0_kernel(
    const float* __restrict__ x, const float* __restrict__ w,
    const float* __restrict__ bias, short* __restrict__ h0) {
  const int b = blockIdx.x >> 10;
  const int t = blockIdx.x & 1023;
  const int c = threadIdx.x;
  __shared__ float xs[3][80];
  for (int i = threadIdx.x; i < 240; i += 256) {
    int dt = i / 80, f = i - dt * 80;
    int tt = t + dt - 1;
    xs[dt][f] = (tt >= 0 && tt < 1024) ? x[(b * 1024 + tt) * 80 + f] : 0.f;
  }
  float wr[9];
#pragma unroll
  for (int i = 0; i < 9; ++i) wr[i] = w[c * 9 + i];
  const float bi = bias[c];
  __syncthreads();
  const int cc = c >> 5, q = (c >> 3) & 3, e = c & 7;
  short* outb = &h0[((size_t)(b * 8 + cc) * 1024 + t) * 832];
  for (int fo = 0; fo < 26; ++fo) {
    float m = -1e30f;
#pragma unroll
    for (int p = 0; p < 3; ++p) {
      const int f = fo * 3 + p;
      float acc = bi;
#pragma unroll
      for (int dt = 0; dt < 3; ++dt)
#pragma unroll
        for (int df = 0; df < 3; ++df)
          acc += xs[dt][f + df] * wr[dt * 3 + df];
      m = fmaxf(m, acc);
    }
    const int row = t * 26 + fo;
    outb[fo * 32 + (q ^ ((row >> 1) & 3)) * 8 + e] = f2bf(fmaxf(m, 0.f));
  }
}

// ---------------------------------------------------------------------------
// Weight pre-transposes (fp32 -> bf16, once per launch)
// ---------------------------------------------------------------------------
// conv1_w [co512][ci256][1][kw12] -> wt1 [cc8][kw12][co512][unit4^swz][8]
__global__ __launch_bounds__(256) void prep_w1(const float* __restrict__ w,
                                               short* __restrict__ wt) {
  const int co = blockIdx.x;
  __shared__ float ls[3072];
  for (int i = threadIdx.x; i < 3072; i += 256) ls[i] = w[co * 3072 + i];
  __syncthreads();
  const int swz = (co >> 1) & 3;
  for (int i = threadIdx.x; i < 3072; i += 256) {
    const int e = i & 7, q = (i >> 3) & 3, kw = (i >> 5) % 12, cc = i / 384;
    const int ci = cc * 32 + q * 8 + e;
    wt[(((size_t)(cc * 12 + kw) * 512 + co) * 4 + (q ^ swz)) * 8 + e] =
        f2bf(ls[ci * 12 + kw]);
  }
}

// conv2_w [co512][ci512][3][3] -> wt2 [cc16][p9][co512][unit4^swz][8]
__global__ __launch_bounds__(256) void prep_w2(const float* __restrict__ w,
                                               short* __restrict__ wt) {
  const int co = blockIdx.x;
  __shared__ float ls[4608];
  for (int i = threadIdx.x; i < 4608; i += 256) ls[i] = w[co * 4608 + i];
  __syncthreads();
  const int swz = (co >> 1) & 3;
  for (int i = threadIdx.x; i < 4608; i += 256) {
    const int e = i & 7, q = (i >> 3) & 3, p = (i >> 5) % 9, cc = i / 288;
    const int ci = cc * 32 + q * 8 + e;
    wt[(((size_t)(cc * 9 + p) * 512 + co) * 4 + (q ^ swz)) * 8 + e] =
        f2bf(ls[ci * 9 + p]);
  }
}

// dense W [K][N] fp32 -> Wt [N][K] bf16 (tiled transpose)
__global__ void prep_wt(const float* __restrict__ w, short* __restrict__ wt,
                        int K, int N) {
  __shared__ float tile[32][33];
  const int k0 = blockIdx.x * 32, n0 = blockIdx.y * 32;
  const int tx = threadIdx.x, ty = threadIdx.y;
  for (int r = ty; r < 32; r += 8) tile[r][tx] = w[(size_t)(k0 + r) * N + n0 + tx];
  __syncthreads();
  for (int r = ty; r < 32; r += 8) wt[(size_t)(n0 + r) * K + k0 + tx] = f2bf(tile[tx][r]);
}

// zero the t=-1 / t=1024 halo slots of h1 (layout [b][cc16][1026][5][32])
__global__ __launch_bounds__(256) void zero_h1_edges(short* __restrict__ h1) {
  short* base = h1 + (size_t)blockIdx.x * 164160;
  for (int i = threadIdx.x; i < 160; i += 256) {
    base[i] = 0;
    base[1025 * 160 + i] = 0;
  }
}

// ---------------------------------------------------------------------------
// conv1 (256->512, 1x12) + pool3 + relu via MFMA GEMM.
// h0 [b][cc8][t][w26][unit^swz] -> h1 [b][cc16][tslot1026][w5][unit^swz]
// Block: co_tile=128, t_tile=32. 8 waves (2co x 4t), wave tile 64co x 128col.
// Per ci-chunk: global_load_lds the contiguous X slice (53.25KB) + all-12-kw
// A slice (96KB), 2 barriers. Reads XOR-swizzled -> 2-way max (free).
// ---------------------------------------------------------------------------
__global__ __launch_bounds__(512) void conv1_kernel(
    const short* __restrict__ h0, const short* __restrict__ wt1,
    const float* __restrict__ bias, short* __restrict__ h1) {
  const int b = blockIdx.x >> 5;
  const int t0 = (blockIdx.x & 31) * 32;
  const int co0 = blockIdx.y * 128;
  __shared__ short XsF[26688];  // 3328 staged units + 8 pad units (row 832)
  __shared__ short AsF[49152];  // 12kw x 512 units
  const int tid = threadIdx.x;
  const int lane = tid & 63;
  const int wid = tid >> 6;
  const int wm = wid >> 2;   // 0..1  (64 co each)
  const int wn = wid & 3;    // 0..3  (8 t each)
  const int l15 = lane & 15, lg = lane >> 4;

  const f32x4 zf = {0.f, 0.f, 0.f, 0.f};
  f32x4 acc[4][8];
#pragma unroll
  for (int i = 0; i < 4; ++i)
#pragma unroll
    for (int j = 0; j < 8; ++j) acc[i][j] = zf;

  for (int cc = 0; cc < 8; ++cc) {
    __syncthreads();  // previous chunk's LDS reads complete
    {
      const short* xs = h0 + ((size_t)(b * 8 + cc) * 1024 + t0) * 832;
#pragma unroll
      for (int i = 0; i < 7; ++i) {
        const int wi = wid + 8 * i;
        if (wi < 52) gld16(xs + wi * 512 + lane * 8, &XsF[wi * 512]);
      }
      const size_t abase = ((size_t)(cc * 12) * 512 + co0) * 32;
#pragma unroll
      for (int i = 0; i < 12; ++i) {
        const int wi = wid + 8 * i;  // 0..95
        const int kw = wi >> 3, r = wi & 7;
        gld16(wt1 + abase + (size_t)kw * 512 * 32 + r * 512 + lane * 8,
              &AsF[wi * 512]);
      }
    }
    __syncthreads();  // staged data visible (vmcnt drained by barrier)
    for (int kw = 0; kw < 12; ++kw) {
      bf16x8 a[4];
#pragma unroll
      for (int sm = 0; sm < 4; ++sm) {
        const int co_l = wm * 64 + sm * 16 + l15;
        a[sm] = *reinterpret_cast<const bf16x8*>(
            &AsF[(kw * 512 + co_l * 4 + (lg ^ ((co_l >> 1) & 3))) * 8]);
      }
#pragma unroll
      for (int sn = 0; sn < 8; ++sn) {
        const int row = (wn * 8 + sn) * 26 + l15 + kw;
        bf16x8 bf = *reinterpret_cast<const bf16x8*>(
            &XsF[(row * 4 + (lg ^ ((row >> 1) & 3))) * 8]);
#pragma unroll
        for (int sm = 0; sm < 4; ++sm)
          acc[sm][sn] = __builtin_amdgcn_mfma_f32_16x16x32_bf16(a[sm], bf, acc[sm][sn], 0, 0, 0);
      }
    }
  }
  // epilogue: pool w-triples (within 16-lane groups) + bias + relu
  const int basel = lane & 48;
  const int wsrc = (l15 < 5) ? 3 * l15 : 0;
#pragma unroll
  for (int sm = 0; sm < 4; ++sm)
#pragma unroll
    for (int sn = 0; sn < 8; ++sn) {
      const int t = t0 + wn * 8 + sn;
#pragma unroll
      for (int r = 0; r < 4; ++r) {
        float val = acc[sm][sn][r];
        float v0 = __shfl(val, basel + wsrc);
        float v1 = __shfl(val, basel + wsrc + 1);
        float v2 = __shfl(val, basel + wsrc + 2);
        if (l15 < 5) {
          const int co = co0 + wm * 64 + sm * 16 + lg * 4 + r;
          float p = fmaxf(fmaxf(v0, v1), v2) + bias[co];
          const int cc2 = co >> 5, q = (co >> 3) & 3, e = co & 7;
          const int row_g = (t + 1) * 5 + l15;
          h1[((size_t)(b * 16 + cc2) * 1026 + (t + 1)) * 160 + l15 * 32 +
             (q ^ ((row_g >> 1) & 3)) * 8 + e] = f2bf(fmaxf(p, 0.f));
        }
      }
    }
}

// ---------------------------------------------------------------------------
// conv2 (512->512, 3x3, pad t +-1) + pool3 + relu via MFMA GEMM ->
// emb_in fp32 [b][t][512].
// h1 [b][cc16][tslot][w5][unit^swz]: chunk slice is contiguous incl. zero halo.
// Block: co_tile=128, t_tile=32 (96 cols = t*3+w). 8 waves (4co x 2col).
// Per chunk: gld X (10.6KB) + all-9-p A (72KB), 2 barriers.
// ---------------------------------------------------------------------------
__global__ __launch_bounds__(512) void conv2_kernel(
    const short* __restrict__ h1, const short* __restrict__ wt2,
    const float* __restrict__ bias, float* __restrict__ emb_in) {
  const int b = blockIdx.x >> 5;
  const int t0 = (blockIdx.x & 31) * 32;
  const int co0 = blockIdx.y * 128;
  __shared__ __align__(16) short XsC[5440];   // 680 units (34 rows x 5w x 4u)
  __shared__ __align__(16) short AsC[36864];  // 9p x 512 units
  float(*Ds)[100] = reinterpret_cast<float(*)[100]>(AsC);  // epilogue overlay 51.2KB
  const int tid = threadIdx.x;
  const int lane = tid & 63;
  const int wid = tid >> 6;
  const int wm = wid >> 1;  // 0..3 (32 co each)
  const int wn = wid & 1;   // 0..1 (48 cols each)
  const int l15 = lane & 15, lg = lane >> 4;
  const f32x4 zf = {0.f, 0.f, 0.f, 0.f};
  f32x4 acc[2][3];
#pragma unroll
  for (int i = 0; i < 2; ++i)
#pragma unroll
    for (int j = 0; j < 3; ++j) acc[i][j] = zf;
  int tl[3], dwl[3];
#pragma unroll
  for (int sn = 0; sn < 3; ++sn) {
    const int c = wn * 48 + sn * 16 + l15;
    tl[sn] = c / 3;
    dwl[sn] = c - tl[sn] * 3;
  }
  for (int cc = 0; cc < 16; ++cc) {
    __syncthreads();
    {
      const short* xs = h1 + ((size_t)(b * 16 + cc) * 1026 + t0) * 160;
#pragma unroll
      for (int i = 0; i < 2; ++i) {
        const int wi = wid + 8 * i;
        if (wi < 11) {
          const int u = wi * 64 + lane;
          if (u < 680) gld16(xs + u * 8, &XsC[wi * 512]);
        }
      }
      const size_t abase = ((size_t)(cc * 9) * 512 + co0) * 32;
#pragma unroll
      for (int i = 0; i < 9; ++i) {
        const int wi = wid + 8 * i;  // 0..71
        const int p = wi >> 3, r = wi & 7;
        gld16(wt2 + abase + (size_t)p * 512 * 32 + r * 512 + lane * 8,
              &AsC[wi * 512]);
      }
    }
    __syncthreads();
#pragma unroll
    for (int p = 0; p < 9; ++p) {
      const int dt = p / 3, dw = p - dt * 3;
      bf16x8 a[2];
#pragma unroll
      for (int sm = 0; sm < 2; ++sm) {
        const int co_l = wm * 32 + sm * 16 + l15;
        a[sm] = *reinterpret_cast<const bf16x8*>(
            &AsC[(p * 512 + co_l * 4 + (lg ^ ((co_l >> 1) & 3))) * 8]);
      }
#pragma unroll
      for (int sn = 0; sn < 3; ++sn) {
        const int row = (tl[sn] + dt) * 5 + dwl[sn] + dw;
        bf16x8 xv = *reinterpret_cast<const bf16x8*>(
            &XsC[(row * 4 + (lg ^ ((row >> 1) & 3))) * 8]);
#pragma unroll
        for (int sm = 0; sm < 2; ++sm)
          acc[sm][sn] = __builtin_amdgcn_mfma_f32_16x16x32_bf16(a[sm], xv, acc[sm][sn], 0, 0, 0);
      }
    }
  }
  __syncthreads();
#pragma unroll
  for (int sm = 0; sm < 2; ++sm)
#pragma unroll
    for (int sn = 0; sn < 3; ++sn)
#pragma unroll
      for (int r = 0; r < 4; ++r)
        Ds[wm * 32 + sm * 16 + lg * 4 + r][wn * 48 + sn * 16 + l15] = acc[sm][sn][r];
  __syncthreads();
  for (int e = tid; e < 4096; e += 512) {
    const int co = e & 127, tt = e >> 7;
    float m = fmaxf(fmaxf(Ds[co][tt * 3], Ds[co][tt * 3 + 1]), Ds[co][tt * 3 + 2]) + bias[co0 + co];
    emb_in[((size_t)(b * 1024) + t0 + tt) * 512 + co0 + co] = fmaxf(m, 0.f);
  }
}

// ---------------------------------------------------------------------------
// LayerNorm kernels. wave-per-row (512 cols, 8 per lane).
// ---------------------------------------------------------------------------
__global__ __launch_bounds__(256) void ln_double_kernel(
    const float* __restrict__ x, const float* __restrict__ g0,
    const float* __restrict__ b0, const float* __restrict__ g1,
    const float* __restrict__ b1, float* __restrict__ o0, float* __restrict__ o1) {
  const int row = blockIdx.x * 4 + (threadIdx.x >> 6);
  const int lane = threadIdx.x & 63;
  const float* xr = x + (size_t)row * 512;
  float v[8];
#pragma unroll
  for (int j = 0; j < 8; ++j) v[j] = xr[j * 64 + lane];
  float s = 0;
#pragma unroll
  for (int j = 0; j < 8; ++j) s += v[j];
  s = wave_sum(s);
  const float mean = s * (1.f / 512.f);
  float q = 0;
#pragma unroll
  for (int j = 0; j < 8; ++j) { float d = v[j] - mean; q += d * d; }
  q = wave_sum(q);
  const float rs = rsqrtf(q * (1.f / 512.f) + 1e-5f);
#pragma unroll
  for (int j = 0; j < 8; ++j) {
    const int ci = j * 64 + lane;
    float e = (v[j] - mean) * rs * g0[ci] + b0[ci];
    o0[(size_t)row * 512 + ci] = e;
    v[j] = e;
  }
  s = 0;
#pragma unroll
  for (int j = 0; j < 8; ++j) s += v[j];
  s = wave_sum(s);
  const float mean2 = s * (1.f / 512.f);
  q = 0;
#pragma unroll
  for (int j = 0; j < 8; ++j) { float d = v[j] - mean2; q += d * d; }
  q = wave_sum(q);
  const float rs2 = rsqrtf(q * (1.f / 512.f) + 1e-5f);
#pragma unroll
  for (int j = 0; j < 8; ++j) {
    const int ci = j * 64 + lane;
    o1[(size_t)row * 512 + ci] = (v[j] - mean2) * rs2 * g1[ci] + b1[ci];
  }
}

__global__ __launch_bounds__(256) void ln_kernel(
    const float* __restrict__ x, const float* __restrict__ g,
    const float* __restrict__ b, float* __restrict__ o) {
  const int row = blockIdx.x * 4 + (threadIdx.x >> 6);
  const int lane = threadIdx.x & 63;
  const float* xr = x + (size_t)row * 512;
  float v[8];
#pragma unroll
  for (int j = 0; j < 8; ++j) v[j] = xr[j * 64 + lane];
  float s = 0;
#pragma unroll
  for (int j = 0; j < 8; ++j) s += v[j];
  s = wave_sum(s);
  const float mean = s * (1.f / 512.f);
  float q = 0;
#pragma unroll
  for (int j = 0; j < 8; ++j) { float d = v[j] - mean; q += d * d; }
  q = wave_sum(q);
  const float rs = rsqrtf(q * (1.f / 512.f) + 1e-5f);
#pragma unroll
  for (int j = 0; j < 8; ++j) {
    const int ci = j * 64 + lane;
    o[(size_t)row * 512 + ci] = (v[j] - mean) * rs * g[ci] + b[ci];
  }
}

// ---------------------------------------------------------------------------
// 1D neighborhood attention (K=7) with rpb. q,k,v fp32 [b][t][h*64+d]
// (q pre-scaled by 1/8 in its GEMM). wave per (b,h,t); lane = d.
// ---------------------------------------------------------------------------
__global__ __launch_bounds__(256) void na1d_kernel(
    const float* __restrict__ q, const float* __restrict__ k,
    const float* __restrict__ v, const float* __restrict__ rpb,
    float* __restrict__ ctx) {
  const int W = blockIdx.x * 4 + (threadIdx.x >> 6);
  const int lane = threadIdx.x & 63;
  const int b = W >> 13, h = (W >> 10) & 7, t = W & 1023;
  int ni = t - 3;
  ni = ni < 0 ? 0 : (ni > 1017 ? 1017 : ni);
  const size_t base = (size_t)(b * 1024) * 512 + h * 64;
  const float qv = q[base + (size_t)t * 512 + lane];
  const float* kb = k + base + (size_t)ni * 512;
  float s[7];
#pragma unroll
  for (int j = 0; j < 7; ++j) {
    float pd = qv * kb[j * 512 + lane];
    pd = wave_sum(pd);
    s[j] = pd + rpb[h * 13 + (ni + j - t + 6)];
  }
  float mx = s[0];
#pragma unroll
  for (int j = 1; j < 7; ++j) mx = fmaxf(mx, s[j]);
  float den = 0;
#pragma unroll
  for (int j = 0; j < 7; ++j) { s[j] = expf(s[j] - mx); den += s[j]; }
  const float inv = 1.f / den;
  const float* vb = v + base + (size_t)ni * 512;
  float o = 0;
#pragma unroll
  for (int j = 0; j < 7; ++j) o += s[j] * vb[j * 512 + lane];
  ctx[base + (size_t)t * 512 + lane] = o * inv;
}

// ---------------------------------------------------------------------------
// Transformer GEMM: C[M=4096][N] = A[M][K] (fp32) x Wt[N][K] (bf16) + bias,
// EPI: 0 = bias, 1 = bias then *0.125 (q), 2 = bias+gelu, 3 = bias+residual.
// Tile 128x64, 4 waves 2x2, BK=32.
// ---------------------------------------------------------------------------
template <int EPI>
__global__ __launch_bounds__(256) void gemm_tf(
    const float* __restrict__ A, const short* __restrict__ Wt,
    const float* __restrict__ bias, const float* __restrict__ res,
    float* __restrict__ C, int K, int N) {
  const int m0 = blockIdx.x * 128, n0 = blockIdx.y * 64;
  __shared__ short Asm[128][40];
  __shared__ short Bsm[64][40];
  const int tid = threadIdx.x;
  const int wid = tid >> 6, lane = tid & 63;
  const int wm = wid >> 1, wn = wid & 1;
  const int l15 = lane & 15, lg = lane >> 4;
  const f32x4 zf = {0.f, 0.f, 0.f, 0.f};
  f32x4 acc[4][2];
#pragma unroll
  for (int i = 0; i < 4; ++i) { acc[i][0] = zf; acc[i][1] = zf; }
  const int ar = tid >> 1, ahf = (tid & 1) * 16;
  for (int k0 = 0; k0 < K; k0 += 32) {
    __syncthreads();
    {
      const float4* s = reinterpret_cast<const float4*>(&A[(size_t)(m0 + ar) * K + k0 + ahf]);
      float4 f0 = s[0], f1 = s[1], f2 = s[2], f3 = s[3];
      short* d = &Asm[ar][ahf];
      d[0] = f2bf(f0.x);  d[1] = f2bf(f0.y);  d[2] = f2bf(f0.z);  d[3] = f2bf(f0.w);
      d[4] = f2bf(f1.x);  d[5] = f2bf(f1.y);  d[6] = f2bf(f1.z);  d[7] = f2bf(f1.w);
      d[8] = f2bf(f2.x);  d[9] = f2bf(f2.y);  d[10] = f2bf(f2.z); d[11] = f2bf(f2.w);
      d[12] = f2bf(f3.x); d[13] = f2bf(f3.y); d[14] = f2bf(f3.z); d[15] = f2bf(f3.w);
    }
    if (tid < 128) {
      const int br = tid >> 1, bhf = (tid & 1) * 16;
      const int4* s = reinterpret_cast<const int4*>(&Wt[(size_t)(n0 + br) * K + k0 + bhf]);
      int4* d = reinterpret_cast<int4*>(&Bsm[br][bhf]);
      d[0] = s[0];
      d[1] = s[1];
    }
    __syncthreads();
    bf16x8 bfr[2];
#pragma unroll
    for (int sn = 0; sn < 2; ++sn)
      bfr[sn] = *reinterpret_cast<const bf16x8*>(&Bsm[wn * 32 + sn * 16 + l15][lg * 8]);
#pragma unroll
    for (int sm = 0; sm < 4; ++sm) {
      bf16x8 a = *reinterpret_cast<const bf16x8*>(&Asm[wm * 64 + sm * 16 + l15][lg * 8]);
#pragma unroll
      for (int sn = 0; sn < 2; ++sn)
        acc[sm][sn] = __builtin_amdgcn_mfma_f32_16x16x32_bf16(a, bfr[sn], acc[sm][sn], 0, 0, 0);
    }
  }
#pragma unroll
  for (int sm = 0; sm < 4; ++sm)
#pragma unroll
    for (int sn = 0; sn < 2; ++sn)
#pragma unroll
      for (int r = 0; r < 4; ++r) {
        const int m = m0 + wm * 64 + sm * 16 + lg * 4 + r;
        const int n = n0 + wn * 32 + sn * 16 + l15;
        float val = acc[sm][sn][r] + bias[n];
        if (EPI == 1) val *= 0.125f;
        if (EPI == 2) val = 0.5f * val * (1.f + erff(val * 0.70710678f));
        if (EPI == 3) val += res[(size_t)m * N + n];
        C[(size_t)m * N + n] = val;
      }
}

// ---------------------------------------------------------------------------
extern "C" void kernel_launch(void* const* d_in, const int* in_sizes, int n_in,
                              void* d_out, int out_size, void* d_ws, size_t ws_size,
                              hipStream_t stream) {
  (void)in_sizes; (void)n_in; (void)out_size;
  const float* x        = (const float*)d_in[0];
  const float* conv0_w  = (const float*)d_in[1];
  const float* conv0_b  = (const float*)d_in[2];
  const float* conv1_w  = (const float*)d_in[3];
  const float* conv1_b  = (const float*)d_in[4];
  const float* conv2_w  = (const float*)d_in[5];
  const float* conv2_b  = (const float*)d_in[6];
  const float* emb_ln_g = (const float*)d_in[7];
  const float* emb_ln_b = (const float*)d_in[8];
  const float* q_w  = (const float*)d_in[9];
  const float* q_b  = (const float*)d_in[10];
  const float* k_w  = (const float*)d_in[11];
  const float* k_b  = (const float*)d_in[12];
  const float* v_w  = (const float*)d_in[13];
  const float* v_b  = (const float*)d_in[14];
  const float* rpb  = (const float*)d_in[15];
  const float* ao_w = (const float*)d_in[16];
  const float* ao_b = (const float*)d_in[17];
  const float* ln1_g = (const float*)d_in[18];
  const float* ln1_b = (const float*)d_in[19];
  const float* ln2_g = (const float*)d_in[20];
  const float* ln2_b = (const float*)d_in[21];
  const float* m1_w = (const float*)d_in[22];
  const float* m1_b = (const float*)d_in[23];
  const float* m2_w = (const float*)d_in[24];
  const float* m2_b = (const float*)d_in[25];

  char* ws = (char*)d_ws;
  size_t off = 0;
  auto alloc = [&](size_t bytes) -> char* {
    char* p = ws + off;
    off += (bytes + 255) & ~(size_t)255;
    return p;
  };
  short* h0   = (short*)alloc(4ull * 8 * 1024 * 832 * 2);     // 54.5 MB
  short* h1   = (short*)alloc(4ull * 16 * 1026 * 160 * 2);    // 21.0 MB
  float* embi = (float*)alloc(4ull * 1024 * 512 * 4);
  float* emb  = (float*)alloc(4ull * 1024 * 512 * 4);
  float* hs1  = (float*)alloc(4ull * 1024 * 512 * 4);
  float* qb   = (float*)alloc(4ull * 1024 * 512 * 4);
  float* kb   = (float*)alloc(4ull * 1024 * 512 * 4);
  float* vb   = (float*)alloc(4ull * 1024 * 512 * 4);
  float* ctx  = (float*)alloc(4ull * 1024 * 512 * 4);
  float* hs   = (float*)alloc(4ull * 1024 * 512 * 4);
  short* wt1  = (short*)alloc(512ull * 12 * 256 * 2);
  short* wt2  = (short*)alloc(512ull * 9 * 512 * 2);
  short* wtq  = (short*)alloc(512ull * 512 * 2);
  short* wtk  = (short*)alloc(512ull * 512 * 2);
  short* wtv  = (short*)alloc(512ull * 512 * 2);
  short* wtao = (short*)alloc(512ull * 512 * 2);
  short* wtm1 = (short*)alloc(2048ull * 512 * 2);
  short* wtm2 = (short*)alloc(512ull * 2048 * 2);
  if (ws_size < off) return;  // fail visibly (poisoned output) instead of OOB
  float* mid  = (float*)h0;   // reuse: 33.5 MB <= 54.5 MB, h0 dead after conv1
  float* ln2o = embi;         // reuse: embi dead after ln_double
  float* outp = (float*)d_out;

  prep_w1<<<512, 256, 0, stream>>>(conv1_w, wt1);
  prep_w2<<<512, 256, 0, stream>>>(conv2_w, wt2);
  zero_h1_edges<<<64, 256, 0, stream>>>(h1);
  dim3 tb(32, 8);
  prep_wt<<<dim3(16, 16), tb, 0, stream>>>(q_w, wtq, 512, 512);
  prep_wt<<<dim3(16, 16), tb, 0, stream>>>(k_w, wtk, 512, 512);
  prep_wt<<<dim3(16, 16), tb, 0, stream>>>(v_w, wtv, 512, 512);
  prep_wt<<<dim3(16, 16), tb, 0, stream>>>(ao_w, wtao, 512, 512);
  prep_wt<<<dim3(16, 64), tb, 0, stream>>>(m1_w, wtm1, 512, 2048);
  prep_wt<<<dim3(64, 16), tb, 0, stream>>>(m2_w, wtm2, 2048, 512);

  conv0_kernel<<<4096, 256, 0, stream>>>(x, conv0_w, conv0_b, h0);
  conv1_kernel<<<dim3(128, 4), 512, 0, stream>>>(h0, wt1, conv1_b, h1);
  conv2_kernel<<<dim3(128, 4), 512, 0, stream>>>(h1, wt2, conv2_b, embi);
  ln_double_kernel<<<1024, 256, 0, stream>>>(embi, emb_ln_g, emb_ln_b, ln1_g, ln1_b, emb, hs1);
  gemm_tf<1><<<dim3(32, 8), 256, 0, stream>>>(hs1, wtq, q_b, nullptr, qb, 512, 512);
  gemm_tf<0><<<dim3(32, 8), 256, 0, stream>>>(hs1, wtk, k_b, nullptr, kb, 512, 512);
  gemm_tf<0><<<dim3(32, 8), 256, 0, stream>>>(hs1, wtv, v_b, nullptr, vb, 512, 512);
  na1d_kernel<<<8192, 256, 0, stream>>>(qb, kb, vb, rpb, ctx);
  gemm_tf<3><<<dim3(32, 8), 256, 0, stream>>>(ctx, wtao, ao_b, emb, hs, 512, 512);
  ln_kernel<<<1024, 256, 0, stream>>>(hs, ln2_g, ln2_b, ln2o);
  gemm_tf<2><<<dim3(32, 32), 256, 0, stream>>>(ln2o, wtm1, m1_b, nullptr, mid, 512, 2048);
  gemm_tf<3><<<dim3(32, 8), 256, 0, stream>>>(mid, wtm2, m2_b, hs, outp, 2048, 512);
}

// Round 5
// 500.759 us; speedup vs baseline: 1.4598x; 1.0124x over previous
//
#include <hip/hip_runtime.h>
#include <hip/hip_bf16.h>
#include <math.h>

// ---------------------------------------------------------------------------
// Model constants
//   B=4, T=1024, F_IN=80, C0=256, C_EMB=512, HEADS=8, K=7, D_HEAD=64, MLP=2048
// ---------------------------------------------------------------------------

typedef __bf16 bf16x8 __attribute__((ext_vector_type(8)));
typedef float f32x4 __attribute__((ext_vector_type(4)));

static __device__ __forceinline__ short f2bf(float f) {
  __hip_bfloat16 h = __float2bfloat16(f);
  return __builtin_bit_cast(short, h);
}

static __device__ __forceinline__ float wave_sum(float v) {
#pragma unroll
  for (int o = 32; o; o >>= 1) v += __shfl_xor(v, o);
  return v;
}

// async global->LDS, 16B per lane; dest = lds_base (wave-uniform) + lane*16
static __device__ __forceinline__ void gld16(const void* g, void* l) {
  __builtin_amdgcn_global_load_lds(
      (const __attribute__((address_space(1))) unsigned int*)g,
      (__attribute__((address_space(3))) unsigned int*)l, 16, 0, 0);
}

// ---------------------------------------------------------------------------
// conv0 (1->256, 3x3, pad t +-1) + maxpool3(w) + relu.  x:[4,1,1024,80] fp32
// out h0 bf16 [b][cc8][t1024][w26][unit4^swz][8]  (chunk-contiguous + swizzled
// 16B units so conv1 can global_load_lds linearly and read conflict-free)
// ---------------------------------------------------------------------------
__global__ __launch_bounds__(256) void conv0_kernel(
    const float* __restrict__ x, const float* __restrict__ w,
    const float* __restrict__ bias, short* __restrict__ h0) {
  const int b = blockIdx.x >> 10;
  const int t = blockIdx.x & 1023;
  const int c = threadIdx.x;
  __shared__ float xs[3][80];
  for (int i = threadIdx.x; i < 240; i += 256) {
    int dt = i / 80, f = i - dt * 80;
    int tt = t + dt - 1;
    xs[dt][f] = (tt >= 0 && tt < 1024) ? x[(b * 1024 + tt) * 80 + f] : 0.f;
  }
  float wr[9];
#pragma unroll
  for (int i = 0; i < 9; ++i) wr[i] = w[c * 9 + i];
  const float bi = bias[c];
  __syncthreads();
  const int cc = c >> 5, q = (c >> 3) & 3, e = c & 7;
  short* outb = &h0[((size_t)(b * 8 + cc) * 1024 + t) * 832];
  for (int fo = 0; fo < 26; ++fo) {
    float m = -1e30f;
#pragma unroll
    for (int p = 0; p < 3; ++p) {
      const int f = fo * 3 + p;
      float acc = bi;
#pragma unroll
      for (int dt = 0; dt < 3; ++dt)
#pragma unroll
        for (int df = 0; df < 3; ++df)
          acc += xs[dt][f + df] * wr[dt * 3 + df];
      m = fmaxf(m, acc);
    }
    const int row = t * 26 + fo;
    outb[fo * 32 + (q ^ ((row >> 1) & 3)) * 8 + e] = f2bf(fmaxf(m, 0.f));
  }
}

// ---------------------------------------------------------------------------
// Weight pre-transposes (fp32 -> bf16, once per launch)
// ---------------------------------------------------------------------------
// conv1_w [co512][ci256][1][kw12] -> wt1 [cc8][kw12][co512][unit4^swz][8]
__global__ __launch_bounds__(256) void prep_w1(const float* __restrict__ w,
                                               short* __restrict__ wt) {
  const int co = blockIdx.x;
  __shared__ float ls[3072];
  for (int i = threadIdx.x; i < 3072; i += 256) ls[i] = w[co * 3072 + i];
  __syncthreads();
  const int swz = (co >> 1) & 3;
  for (int i = threadIdx.x; i < 3072; i += 256) {
    const int e = i & 7, q = (i >> 3) & 3, kw = (i >> 5) % 12, cc = i / 384;
    const int ci = cc * 32 + q * 8 + e;
    wt[(((size_t)(cc * 12 + kw) * 512 + co) * 4 + (q ^ swz)) * 8 + e] =
        f2bf(ls[ci * 12 + kw]);
  }
}

// conv2_w [co512][ci512][3][3] -> wt2 [cc16][p9][co512][unit4^swz][8]
__global__ __launch_bounds__(256) void prep_w2(const float* __restrict__ w,
                                               short* __restrict__ wt) {
  const int co = blockIdx.x;
  __shared__ float ls[4608];
  for (int i = threadIdx.x; i < 4608; i += 256) ls[i] = w[co * 4608 + i];
  __syncthreads();
  const int swz = (co >> 1) & 3;
  for (int i = threadIdx.x; i < 4608; i += 256) {
    const int e = i & 7, q = (i >> 3) & 3, p = (i >> 5) % 9, cc = i / 288;
    const int ci = cc * 32 + q * 8 + e;
    wt[(((size_t)(cc * 9 + p) * 512 + co) * 4 + (q ^ swz)) * 8 + e] =
        f2bf(ls[ci * 9 + p]);
  }
}

// dense W [K][N] fp32 -> Wt [N][K] bf16 (tiled transpose)
__global__ void prep_wt(const float* __restrict__ w, short* __restrict__ wt,
                        int K, int N) {
  __shared__ float tile[32][33];
  const int k0 = blockIdx.x * 32, n0 = blockIdx.y * 32;
  const int tx = threadIdx.x, ty = threadIdx.y;
  for (int r = ty; r < 32; r += 8) tile[r][tx] = w[(size_t)(k0 + r) * N + n0 + tx];
  __syncthreads();
  for (int r = ty; r < 32; r += 8) wt[(size_t)(n0 + r) * K + k0 + tx] = f2bf(tile[tx][r]);
}

// zero the t=-1 / t=1024 halo slots of h1 (layout [b][cc16][1026][5][32])
__global__ __launch_bounds__(256) void zero_h1_edges(short* __restrict__ h1) {
  short* base = h1 + (size_t)blockIdx.x * 164160;
  for (int i = threadIdx.x; i < 160; i += 256) {
    base[i] = 0;
    base[1025 * 160 + i] = 0;
  }
}

// ---------------------------------------------------------------------------
// conv1 (256->512, 1x12) + pool3 + relu via MFMA GEMM, T3 2-phase pipeline.
// h0 [b][cc8][t][w26][unit^swz] -> h1 [b][cc16][tslot1026][w5][unit^swz]
// Block: co_tile=128, t_tile=32, 8 waves, wave tile 64co x 128col.
// 32 steps (8 ci-chunks x 4 kw-groups of 3). Per step: issue next step's
// global_load_lds (A group, + X chunk at group boundary), compute current
// step from the other buffer, ONE __syncthreads (drain finds loads done).
// LDS: X dbuf 2x53.4KB + A dbuf 2x24.6KB = 152KB. Reads swizzled (<=2-way).
// ---------------------------------------------------------------------------
__global__ __launch_bounds__(512) void conv1_kernel(
    const short* __restrict__ h0, const short* __restrict__ wt1,
    const float* __restrict__ bias, short* __restrict__ h1) {
  const int b = blockIdx.x >> 5;
  const int t0 = (blockIdx.x & 31) * 32;
  const int co0 = blockIdx.y * 128;
  __shared__ short XsF[2][26688];   // 53376 B each half incl. 4-unit tail pad
  __shared__ short AsF[2][12288];   // 3kw x 512 units
  const int tid = threadIdx.x;
  const int lane = tid & 63;
  const int wid = tid >> 6;
  const int wm = wid >> 2;   // 0..1  (64 co each)
  const int wn = wid & 3;    // 0..3  (8 t each)
  const int l15 = lane & 15, lg = lane >> 4;

  const f32x4 zf = {0.f, 0.f, 0.f, 0.f};
  f32x4 acc[4][8];
#pragma unroll
  for (int i = 0; i < 4; ++i)
#pragma unroll
    for (int j = 0; j < 8; ++j) acc[i][j] = zf;

  auto stageX = [&](int cc, int buf) {
    const short* xs = h0 + ((size_t)(b * 8 + cc) * 1024 + t0) * 832;
#pragma unroll
    for (int i = 0; i < 7; ++i) {
      const int v = wid + 8 * i;
      if (v < 52) gld16(xs + v * 512 + lane * 8, &XsF[buf][v * 512]);
    }
  };
  auto stageA = [&](int cc, int g, int buf) {
#pragma unroll
    for (int i = 0; i < 3; ++i) {
      const int u = wid * 3 + i;      // 0..23
      const int kwl = u >> 3, r = u & 7;
      gld16(wt1 + ((size_t)((cc * 12 + g * 3 + kwl) * 512) + co0) * 32 +
                r * 512 + lane * 8,
            &AsF[buf][kwl * 4096 + r * 512]);
    }
  };

  stageX(0, 0);
  stageA(0, 0, 0);
  __syncthreads();

  for (int s = 0; s < 32; ++s) {
    const int cc = s >> 2, g = s & 3;
    if (s < 31) {
      const int s1 = s + 1;
      const int cc1 = s1 >> 2, g1 = s1 & 3;
      stageA(cc1, g1, s1 & 1);
      if (g1 == 0) stageX(cc1, cc1 & 1);
    }
    const short* Xb = XsF[cc & 1];
    const short* Ab = AsF[s & 1];
#pragma unroll
    for (int j = 0; j < 3; ++j) {
      const int kw = g * 3 + j;
      bf16x8 a[4];
#pragma unroll
      for (int sm = 0; sm < 4; ++sm) {
        const int co_l = wm * 64 + sm * 16 + l15;
        a[sm] = *reinterpret_cast<const bf16x8*>(
            &Ab[(j * 512 + co_l * 4 + (lg ^ ((co_l >> 1) & 3))) * 8]);
      }
#pragma unroll
      for (int sn = 0; sn < 8; ++sn) {
        const int row = (wn * 8 + sn) * 26 + l15 + kw;
        bf16x8 bf = *reinterpret_cast<const bf16x8*>(
            &Xb[(row * 4 + (lg ^ ((row >> 1) & 3))) * 8]);
#pragma unroll
        for (int sm = 0; sm < 4; ++sm)
          acc[sm][sn] = __builtin_amdgcn_mfma_f32_16x16x32_bf16(a[sm], bf, acc[sm][sn], 0, 0, 0);
      }
    }
    __syncthreads();
  }
  // epilogue: pool w-triples (within 16-lane groups) + bias + relu
  const int basel = lane & 48;
  const int wsrc = (l15 < 5) ? 3 * l15 : 0;
#pragma unroll
  for (int sm = 0; sm < 4; ++sm)
#pragma unroll
    for (int sn = 0; sn < 8; ++sn) {
      const int t = t0 + wn * 8 + sn;
#pragma unroll
      for (int r = 0; r < 4; ++r) {
        float val = acc[sm][sn][r];
        float v0 = __shfl(val, basel + wsrc);
        float v1 = __shfl(val, basel + wsrc + 1);
        float v2 = __shfl(val, basel + wsrc + 2);
        if (l15 < 5) {
          const int co = co0 + wm * 64 + sm * 16 + lg * 4 + r;
          float p = fmaxf(fmaxf(v0, v1), v2) + bias[co];
          const int cc2 = co >> 5, q = (co >> 3) & 3, e = co & 7;
          const int row_g = (t + 1) * 5 + l15;
          h1[((size_t)(b * 16 + cc2) * 1026 + (t + 1)) * 160 + l15 * 32 +
             (q ^ ((row_g >> 1) & 3)) * 8 + e] = f2bf(fmaxf(p, 0.f));
        }
      }
    }
}

// ---------------------------------------------------------------------------
// conv2 (512->512, 3x3, pad t +-1) + pool3 + relu, T3 2-phase pipeline ->
// emb_in fp32 [b][t][512].
// Block: co_tile=128, t_tile=32 (96 cols = t*3+w). 8 waves (4co x 2col).
// 48 steps (16 ci-chunks x 3 tap-rows: dt=g, dw=j). LDS 70KB -> 2 blocks/CU.
// Buffers addressed by integer offsets (no LDS pointer arrays).
// ---------------------------------------------------------------------------
__global__ __launch_bounds__(512) void conv2_kernel(
    const short* __restrict__ h1, const short* __restrict__ wt2,
    const float* __restrict__ bias, float* __restrict__ emb_in) {
  const int b = blockIdx.x >> 5;
  const int t0 = (blockIdx.x & 31) * 32;
  const int co0 = blockIdx.y * 128;
  __shared__ __align__(16) short smem2[35840];  // 71680 B
  // layout: X buf0 @0, X buf1 @5632, A buf0 @11264, A buf1 @23552 (shorts)
  const int tid = threadIdx.x;
  const int lane = tid & 63;
  const int wid = tid >> 6;
  const int wm = wid >> 1;  // 0..3 (32 co each)
  const int wn = wid & 1;   // 0..1 (48 cols each)
  const int l15 = lane & 15, lg = lane >> 4;
  const f32x4 zf = {0.f, 0.f, 0.f, 0.f};
  f32x4 acc[2][3];
#pragma unroll
  for (int i = 0; i < 2; ++i)
#pragma unroll
    for (int j = 0; j < 3; ++j) acc[i][j] = zf;
  int tl[3], dwl[3];
#pragma unroll
  for (int sn = 0; sn < 3; ++sn) {
    const int c = wn * 48 + sn * 16 + l15;
    tl[sn] = c / 3;
    dwl[sn] = c - tl[sn] * 3;
  }

  auto stageX = [&](int cc, int buf) {
    const short* xs = h1 + ((size_t)(b * 16 + cc) * 1026 + t0) * 160;
#pragma unroll
    for (int i = 0; i < 2; ++i) {
      const int v = wid + 8 * i;
      if (v < 11) gld16(xs + v * 512 + lane * 8, &smem2[buf * 5632 + v * 512]);
    }
  };
  auto stageA = [&](int cc, int g, int buf) {
#pragma unroll
    for (int i = 0; i < 3; ++i) {
      const int u = wid * 3 + i;      // 0..23
      const int pl = u >> 3, r = u & 7;
      gld16(wt2 + ((size_t)((cc * 9 + g * 3 + pl) * 512) + co0) * 32 +
                r * 512 + lane * 8,
            &smem2[11264 + buf * 12288 + pl * 4096 + r * 512]);
    }
  };

  stageX(0, 0);
  stageA(0, 0, 0);
  __syncthreads();

  for (int s = 0; s < 48; ++s) {
    const int cc = s / 3, g = s - cc * 3;
    if (s < 47) {
      const int s1 = s + 1;
      const int cc1 = s1 / 3, g1 = s1 - cc1 * 3;
      stageA(cc1, g1, s1 & 1);
      if (g1 == 0) stageX(cc1, cc1 & 1);
    }
    const short* Xb = &smem2[(cc & 1) * 5632];
    const short* Ab = &smem2[11264 + (s & 1) * 12288];
#pragma unroll
    for (int j = 0; j < 3; ++j) {   // p = g*3+j -> dt=g, dw=j
      bf16x8 a[2];
#pragma unroll
      for (int sm = 0; sm < 2; ++sm) {
        const int co_l = wm * 32 + sm * 16 + l15;
        a[sm] = *reinterpret_cast<const bf16x8*>(
            &Ab[(j * 512 + co_l * 4 + (lg ^ ((co_l >> 1) & 3))) * 8]);
      }
#pragma unroll
      for (int sn = 0; sn < 3; ++sn) {
        const int row = (tl[sn] + g) * 5 + dwl[sn] + j;
        bf16x8 xv = *reinterpret_cast<const bf16x8*>(
            &Xb[(row * 4 + (lg ^ ((row >> 1) & 3))) * 8]);
#pragma unroll
        for (int sm = 0; sm < 2; ++sm)
          acc[sm][sn] = __builtin_amdgcn_mfma_f32_16x16x32_bf16(a[sm], xv, acc[sm][sn], 0, 0, 0);
      }
    }
    __syncthreads();
  }
  float(*Ds)[100] = reinterpret_cast<float(*)[100]>(smem2);  // epilogue overlay
#pragma unroll
  for (int sm = 0; sm < 2; ++sm)
#pragma unroll
    for (int sn = 0; sn < 3; ++sn)
#pragma unroll
      for (int r = 0; r < 4; ++r)
        Ds[wm * 32 + sm * 16 + lg * 4 + r][wn * 48 + sn * 16 + l15] = acc[sm][sn][r];
  __syncthreads();
  for (int e = tid; e < 4096; e += 512) {
    const int co = e & 127, tt = e >> 7;
    float m = fmaxf(fmaxf(Ds[co][tt * 3], Ds[co][tt * 3 + 1]), Ds[co][tt * 3 + 2]) + bias[co0 + co];
    emb_in[((size_t)(b * 1024) + t0 + tt) * 512 + co0 + co] = fmaxf(m, 0.f);
  }
}

// ---------------------------------------------------------------------------
// LayerNorm kernels. wave-per-row (512 cols, 8 per lane).
// ---------------------------------------------------------------------------
__global__ __launch_bounds__(256) void ln_double_kernel(
    const float* __restrict__ x, const float* __restrict__ g0,
    const float* __restrict__ b0, const float* __restrict__ g1,
    const float* __restrict__ b1, float* __restrict__ o0, float* __restrict__ o1) {
  const int row = blockIdx.x * 4 + (threadIdx.x >> 6);
  const int lane = threadIdx.x & 63;
  const float* xr = x + (size_t)row * 512;
  float v[8];
#pragma unroll
  for (int j = 0; j < 8; ++j) v[j] = xr[j * 64 + lane];
  float s = 0;
#pragma unroll
  for (int j = 0; j < 8; ++j) s += v[j];
  s = wave_sum(s);
  const float mean = s * (1.f / 512.f);
  float q = 0;
#pragma unroll
  for (int j = 0; j < 8; ++j) { float d = v[j] - mean; q += d * d; }
  q = wave_sum(q);
  const float rs = rsqrtf(q * (1.f / 512.f) + 1e-5f);
#pragma unroll
  for (int j = 0; j < 8; ++j) {
    const int ci = j * 64 + lane;
    float e = (v[j] - mean) * rs * g0[ci] + b0[ci];
    o0[(size_t)row * 512 + ci] = e;
    v[j] = e;
  }
  s = 0;
#pragma unroll
  for (int j = 0; j < 8; ++j) s += v[j];
  s = wave_sum(s);
  const float mean2 = s * (1.f / 512.f);
  q = 0;
#pragma unroll
  for (int j = 0; j < 8; ++j) { float d = v[j] - mean2; q += d * d; }
  q = wave_sum(q);
  const float rs2 = rsqrtf(q * (1.f / 512.f) + 1e-5f);
#pragma unroll
  for (int j = 0; j < 8; ++j) {
    const int ci = j * 64 + lane;
    o1[(size_t)row * 512 + ci] = (v[j] - mean2) * rs2 * g1[ci] + b1[ci];
  }
}

__global__ __launch_bounds__(256) void ln_kernel(
    const float* __restrict__ x, const float* __restrict__ g,
    const float* __restrict__ b, float* __restrict__ o) {
  const int row = blockIdx.x * 4 + (threadIdx.x >> 6);
  const int lane = threadIdx.x & 63;
  const float* xr = x + (size_t)row * 512;
  float v[8];
#pragma unroll
  for (int j = 0; j < 8; ++j) v[j] = xr[j * 64 + lane];
  float s = 0;
#pragma unroll
  for (int j = 0; j < 8; ++j) s += v[j];
  s = wave_sum(s);
  const float mean = s * (1.f / 512.f);
  float q = 0;
#pragma unroll
  for (int j = 0; j < 8; ++j) { float d = v[j] - mean; q += d * d; }
  q = wave_sum(q);
  const float rs = rsqrtf(q * (1.f / 512.f) + 1e-5f);
#pragma unroll
  for (int j = 0; j < 8; ++j) {
    const int ci = j * 64 + lane;
    o[(size_t)row * 512 + ci] = (v[j] - mean) * rs * g[ci] + b[ci];
  }
}

// ---------------------------------------------------------------------------
// 1D neighborhood attention (K=7) with rpb. q,k,v fp32 [b][t][h*64+d]
// (q pre-scaled by 1/8 in its GEMM). wave per (b,h,t); lane = d.
// ---------------------------------------------------------------------------
__global__ __launch_bounds__(256) void na1d_kernel(
    const float* __restrict__ q, const float* __restrict__ k,
    const float* __restrict__ v, const float* __restrict__ rpb,
    float* __restrict__ ctx) {
  const int W = blockIdx.x * 4 + (threadIdx.x >> 6);
  const int lane = threadIdx.x & 63;
  const int b = W >> 13, h = (W >> 10) & 7, t = W & 1023;
  int ni = t - 3;
  ni = ni < 0 ? 0 : (ni > 1017 ? 1017 : ni);
  const size_t base = (size_t)(b * 1024) * 512 + h * 64;
  const float qv = q[base + (size_t)t * 512 + lane];
  const float* kb = k + base + (size_t)ni * 512;
  float s[7];
#pragma unroll
  for (int j = 0; j < 7; ++j) {
    float pd = qv * kb[j * 512 + lane];
    pd = wave_sum(pd);
    s[j] = pd + rpb[h * 13 + (ni + j - t + 6)];
  }
  float mx = s[0];
#pragma unroll
  for (int j = 1; j < 7; ++j) mx = fmaxf(mx, s[j]);
  float den = 0;
#pragma unroll
  for (int j = 0; j < 7; ++j) { s[j] = expf(s[j] - mx); den += s[j]; }
  const float inv = 1.f / den;
  const float* vb = v + base + (size_t)ni * 512;
  float o = 0;
#pragma unroll
  for (int j = 0; j < 7; ++j) o += s[j] * vb[j * 512 + lane];
  ctx[base + (size_t)t * 512 + lane] = o * inv;
}

// ---------------------------------------------------------------------------
// Transformer GEMM: C[M=4096][N] = A[M][K] (fp32) x Wt[N][K] (bf16) + bias,
// EPI: 0 = bias, 1 = bias then *0.125 (q), 2 = bias+gelu, 3 = bias+residual.
// Tile 128x64, 4 waves 2x2, BK=32.
// ---------------------------------------------------------------------------
template <int EPI>
__global__ __launch_bounds__(256) void gemm_tf(
    const float* __restrict__ A, const short* __restrict__ Wt,
    const float* __restrict__ bias, const float* __restrict__ res,
    float* __restrict__ C, int K, int N) {
  const int m0 = blockIdx.x * 128, n0 = blockIdx.y * 64;
  __shared__ short Asm[128][40];
  __shared__ short Bsm[64][40];
  const int tid = threadIdx.x;
  const int wid = tid >> 6, lane = tid & 63;
  const int wm = wid >> 1, wn = wid & 1;
  const int l15 = lane & 15, lg = lane >> 4;
  const f32x4 zf = {0.f, 0.f, 0.f, 0.f};
  f32x4 acc[4][2];
#pragma unroll
  for (int i = 0; i < 4; ++i) { acc[i][0] = zf; acc[i][1] = zf; }
  const int ar = tid >> 1, ahf = (tid & 1) * 16;
  for (int k0 = 0; k0 < K; k0 += 32) {
    __syncthreads();
    {
      const float4* s = reinterpret_cast<const float4*>(&A[(size_t)(m0 + ar) * K + k0 + ahf]);
      float4 f0 = s[0], f1 = s[1], f2 = s[2], f3 = s[3];
      short* d = &Asm[ar][ahf];
      d[0] = f2bf(f0.x);  d[1] = f2bf(f0.y);  d[2] = f2bf(f0.z);  d[3] = f2bf(f0.w);
      d[4] = f2bf(f1.x);  d[5] = f2bf(f1.y);  d[6] = f2bf(f1.z);  d[7] = f2bf(f1.w);
      d[8] = f2bf(f2.x);  d[9] = f2bf(f2.y);  d[10] = f2bf(f2.z); d[11] = f2bf(f2.w);
      d[12] = f2bf(f3.x); d[13] = f2bf(f3.y); d[14] = f2bf(f3.z); d[15] = f2bf(f3.w);
    }
    if (tid < 128) {
      const int br = tid >> 1, bhf = (tid & 1) * 16;
      const int4* s = reinterpret_cast<const int4*>(&Wt[(size_t)(n0 + br) * K + k0 + bhf]);
      int4* d = reinterpret_cast<int4*>(&Bsm[br][bhf]);
      d[0] = s[0];
      d[1] = s[1];
    }
    __syncthreads();
    bf16x8 bfr[2];
#pragma unroll
    for (int sn = 0; sn < 2; ++sn)
      bfr[sn] = *reinterpret_cast<const bf16x8*>(&Bsm[wn * 32 + sn * 16 + l15][lg * 8]);
#pragma unroll
    for (int sm = 0; sm < 4; ++sm) {
      bf16x8 a = *reinterpret_cast<const bf16x8*>(&Asm[wm * 64 + sm * 16 + l15][lg * 8]);
#pragma unroll
      for (int sn = 0; sn < 2; ++sn)
        acc[sm][sn] = __builtin_amdgcn_mfma_f32_16x16x32_bf16(a, bfr[sn], acc[sm][sn], 0, 0, 0);
    }
  }
#pragma unroll
  for (int sm = 0; sm < 4; ++sm)
#pragma unroll
    for (int sn = 0; sn < 2; ++sn)
#pragma unroll
      for (int r = 0; r < 4; ++r) {
        const int m = m0 + wm * 64 + sm * 16 + lg * 4 + r;
        const int n = n0 + wn * 32 + sn * 16 + l15;
        float val = acc[sm][sn][r] + bias[n];
        if (EPI == 1) val *= 0.125f;
        if (EPI == 2) val = 0.5f * val * (1.f + erff(val * 0.70710678f));
        if (EPI == 3) val += res[(size_t)m * N + n];
        C[(size_t)m * N + n] = val;
      }
}

// ---------------------------------------------------------------------------
extern "C" void kernel_launch(void* const* d_in, const int* in_sizes, int n_in,
                              void* d_out, int out_size, void* d_ws, size_t ws_size,
                              hipStream_t stream) {
  (void)in_sizes; (void)n_in; (void)out_size;
  const float* x        = (const float*)d_in[0];
  const float* conv0_w  = (const float*)d_in[1];
  const float* conv0_b  = (const float*)d_in[2];
  const float* conv1_w  = (const float*)d_in[3];
  const float* conv1_b  = (const float*)d_in[4];
  const float* conv2_w  = (const float*)d_in[5];
  const float* conv2_b  = (const float*)d_in[6];
  const float* emb_ln_g = (const float*)d_in[7];
  const float* emb_ln_b = (const float*)d_in[8];
  const float* q_w  = (const float*)d_in[9];
  const float* q_b  = (const float*)d_in[10];
  const float* k_w  = (const float*)d_in[11];
  const float* k_b  = (const float*)d_in[12];
  const float* v_w  = (const float*)d_in[13];
  const float* v_b  = (const float*)d_in[14];
  const float* rpb  = (const float*)d_in[15];
  const float* ao_w = (const float*)d_in[16];
  const float* ao_b = (const float*)d_in[17];
  const float* ln1_g = (const float*)d_in[18];
  const float* ln1_b = (const float*)d_in[19];
  const float* ln2_g = (const float*)d_in[20];
  const float* ln2_b = (const float*)d_in[21];
  const float* m1_w = (const float*)d_in[22];
  const float* m1_b = (const float*)d_in[23];
  const float* m2_w = (const float*)d_in[24];
  const float* m2_b = (const float*)d_in[25];

  char* ws = (char*)d_ws;
  size_t off = 0;
  auto alloc = [&](size_t bytes) -> char* {
    char* p = ws + off;
    off += (bytes + 255) & ~(size_t)255;
    return p;
  };
  short* h0   = (short*)alloc(4ull * 8 * 1024 * 832 * 2);     // 54.5 MB
  short* h1   = (short*)alloc(4ull * 16 * 1026 * 160 * 2);    // 21.0 MB
  float* embi = (float*)alloc(4ull * 1024 * 512 * 4);
  float* emb  = (float*)alloc(4ull * 1024 * 512 * 4);
  float* hs1  = (float*)alloc(4ull * 1024 * 512 * 4);
  float* qb   = (float*)alloc(4ull * 1024 * 512 * 4);
  float* kb   = (float*)alloc(4ull * 1024 * 512 * 4);
  float* vb   = (float*)alloc(4ull * 1024 * 512 * 4);
  float* ctx  = (float*)alloc(4ull * 1024 * 512 * 4);
  float* hs   = (float*)alloc(4ull * 1024 * 512 * 4);
  short* wt1  = (short*)alloc(512ull * 12 * 256 * 2);
  short* wt2  = (short*)alloc(512ull * 9 * 512 * 2);
  short* wtq  = (short*)alloc(512ull * 512 * 2);
  short* wtk  = (short*)alloc(512ull * 512 * 2);
  short* wtv  = (short*)alloc(512ull * 512 * 2);
  short* wtao = (short*)alloc(512ull * 512 * 2);
  short* wtm1 = (short*)alloc(2048ull * 512 * 2);
  short* wtm2 = (short*)alloc(512ull * 2048 * 2);
  if (ws_size < off) return;  // fail visibly (poisoned output) instead of OOB
  float* mid  = (float*)h0;   // reuse: 33.5 MB <= 54.5 MB, h0 dead after conv1
  float* ln2o = embi;         // reuse: embi dead after ln_double
  float* outp = (float*)d_out;

  prep_w1<<<512, 256, 0, stream>>>(conv1_w, wt1);
  prep_w2<<<512, 256, 0, stream>>>(conv2_w, wt2);
  zero_h1_edges<<<64, 256, 0, stream>>>(h1);
  dim3 tb(32, 8);
  prep_wt<<<dim3(16, 16), tb, 0, stream>>>(q_w, wtq, 512, 512);
  prep_wt<<<dim3(16, 16), tb, 0, stream>>>(k_w, wtk, 512, 512);
  prep_wt<<<dim3(16, 16), tb, 0, stream>>>(v_w, wtv, 512, 512);
  prep_wt<<<dim3(16, 16), tb, 0, stream>>>(ao_w, wtao, 512, 512);
  prep_wt<<<dim3(16, 64), tb, 0, stream>>>(m1_w, wtm1, 512, 2048);
  prep_wt<<<dim3(64, 16), tb, 0, stream>>>(m2_w, wtm2, 2048, 512);

  conv0_kernel<<<4096, 256, 0, stream>>>(x, conv0_w, conv0_b, h0);
  conv1_kernel<<<dim3(128, 4), 512, 0, stream>>>(h0, wt1, conv1_b, h1);
  conv2_kernel<<<dim3(128, 4), 512, 0, stream>>>(h1, wt2, conv2_b, embi);
  ln_double_kernel<<<1024, 256, 0, stream>>>(embi, emb_ln_g, emb_ln_b, ln1_g, ln1_b, emb, hs1);
  gemm_tf<1><<<dim3(32, 8), 256, 0, stream>>>(hs1, wtq, q_b, nullptr, qb, 512, 512);
  gemm_tf<0><<<dim3(32, 8), 256, 0, stream>>>(hs1, wtk, k_b, nullptr, kb, 512, 512);
  gemm_tf<0><<<dim3(32, 8), 256, 0, stream>>>(hs1, wtv, v_b, nullptr, vb, 512, 512);
  na1d_kernel<<<8192, 256, 0, stream>>>(qb, kb, vb, rpb, ctx);
  gemm_tf<3><<<dim3(32, 8), 256, 0, stream>>>(ctx, wtao, ao_b, emb, hs, 512, 512);
  ln_kernel<<<1024, 256, 0, stream>>>(hs, ln2_g, ln2_b, ln2o);
  gemm_tf<2><<<dim3(32, 32), 256, 0, stream>>>(ln2o, wtm1, m1_b, nullptr, mid, 512, 2048);
  gemm_tf<3><<<dim3(32, 8), 256, 0, stream>>>(mid, wtm2, m2_b, hs, outp, 2048, 512);
}

// Round 6
// 499.451 us; speedup vs baseline: 1.4637x; 1.0026x over previous
//
#include <hip/hip_runtime.h>
#include <hip/hip_bf16.h>
#include <math.h>

// ---------------------------------------------------------------------------
// Model constants
//   B=4, T=1024, F_IN=80, C0=256, C_EMB=512, HEADS=8, K=7, D_HEAD=64, MLP=2048
// ---------------------------------------------------------------------------

typedef __bf16 bf16x8 __attribute__((ext_vector_type(8)));
typedef float f32x4 __attribute__((ext_vector_type(4)));

static __device__ __forceinline__ short f2bf(float f) {
  __hip_bfloat16 h = __float2bfloat16(f);
  return __builtin_bit_cast(short, h);
}

static __device__ __forceinline__ float wave_sum(float v) {
#pragma unroll
  for (int o = 32; o; o >>= 1) v += __shfl_xor(v, o);
  return v;
}

// async global->LDS, 16B per lane; dest = lds_base (wave-uniform) + lane*16
static __device__ __forceinline__ void gld16(const void* g, void* l) {
  __builtin_amdgcn_global_load_lds(
      (const __attribute__((address_space(1))) unsigned int*)g,
      (__attribute__((address_space(3))) unsigned int*)l, 16, 0, 0);
}

// ---------------------------------------------------------------------------
// conv0 (1->256, 3x3, pad t +-1) + maxpool3(w) + relu.  x:[4,1,1024,80] fp32
// out h0 bf16 [b][cc8][t1024][w28][unit4^swz][8]  (w=26,27 are zero pads so
// conv1's X stage is exactly 56 wave-loads = 7 per wave, uniform)
// ---------------------------------------------------------------------------
__global__ __launch_bounds__(256) void conv0_kernel(
    const float* __restrict__ x, const float* __restrict__ w,
    const float* __restrict__ bias, short* __restrict__ h0) {
  const int b = blockIdx.x >> 10;
  const int t = blockIdx.x & 1023;
  const int c = threadIdx.x;
  __shared__ float xs[3][80];
  for (int i = threadIdx.x; i < 240; i += 256) {
    int dt = i / 80, f = i - dt * 80;
    int tt = t + dt - 1;
    xs[dt][f] = (tt >= 0 && tt < 1024) ? x[(b * 1024 + tt) * 80 + f] : 0.f;
  }
  float wr[9];
#pragma unroll
  for (int i = 0; i < 9; ++i) wr[i] = w[c * 9 + i];
  const float bi = bias[c];
  __syncthreads();
  const int cc = c >> 5, q = (c >> 3) & 3, e = c & 7;
  short* outb = &h0[((size_t)(b * 8 + cc) * 1024 + t) * 896];
  for (int fo = 0; fo < 26; ++fo) {
    float m = -1e30f;
#pragma unroll
    for (int p = 0; p < 3; ++p) {
      const int f = fo * 3 + p;
      float acc = bi;
#pragma unroll
      for (int dt = 0; dt < 3; ++dt)
#pragma unroll
        for (int df = 0; df < 3; ++df)
          acc += xs[dt][f + df] * wr[dt * 3 + df];
      m = fmaxf(m, acc);
    }
    const int row = t * 28 + fo;
    outb[fo * 32 + (q ^ ((row >> 1) & 3)) * 8 + e] = f2bf(fmaxf(m, 0.f));
  }
  if (c < 64) outb[832 + c] = 0;  // zero pad rows w=26,27
}

// ---------------------------------------------------------------------------
// Weight pre-transposes (fp32 -> bf16, once per launch)
// ---------------------------------------------------------------------------
// conv1_w [co512][ci256][1][kw12] -> wt1 [cc8][kw12][co512][unit4^swz][8]
__global__ __launch_bounds__(256) void prep_w1(const float* __restrict__ w,
                                               short* __restrict__ wt) {
  const int co = blockIdx.x;
  __shared__ float ls[3072];
  for (int i = threadIdx.x; i < 3072; i += 256) ls[i] = w[co * 3072 + i];
  __syncthreads();
  const int swz = (co >> 1) & 3;
  for (int i = threadIdx.x; i < 3072; i += 256) {
    const int e = i & 7, q = (i >> 3) & 3, kw = (i >> 5) % 12, cc = i / 384;
    const int ci = cc * 32 + q * 8 + e;
    wt[(((size_t)(cc * 12 + kw) * 512 + co) * 4 + (q ^ swz)) * 8 + e] =
        f2bf(ls[ci * 12 + kw]);
  }
}

// conv2_w [co512][ci512][3][3] -> wt2 [cc16][p9][co512][unit4^swz][8]
__global__ __launch_bounds__(256) void prep_w2(const float* __restrict__ w,
                                               short* __restrict__ wt) {
  const int co = blockIdx.x;
  __shared__ float ls[4608];
  for (int i = threadIdx.x; i < 4608; i += 256) ls[i] = w[co * 4608 + i];
  __syncthreads();
  const int swz = (co >> 1) & 3;
  for (int i = threadIdx.x; i < 4608; i += 256) {
    const int e = i & 7, q = (i >> 3) & 3, p = (i >> 5) % 9, cc = i / 288;
    const int ci = cc * 32 + q * 8 + e;
    wt[(((size_t)(cc * 9 + p) * 512 + co) * 4 + (q ^ swz)) * 8 + e] =
        f2bf(ls[ci * 9 + p]);
  }
}

// dense W [K][N] fp32 -> Wt [N][K] bf16 (tiled transpose)
__global__ void prep_wt(const float* __restrict__ w, short* __restrict__ wt,
                        int K, int N) {
  __shared__ float tile[32][33];
  const int k0 = blockIdx.x * 32, n0 = blockIdx.y * 32;
  const int tx = threadIdx.x, ty = threadIdx.y;
  for (int r = ty; r < 32; r += 8) tile[r][tx] = w[(size_t)(k0 + r) * N + n0 + tx];
  __syncthreads();
  for (int r = ty; r < 32; r += 8) wt[(size_t)(n0 + r) * K + k0 + tx] = f2bf(tile[tx][r]);
}

// zero the t=-1 / t=1024 halo slots of h1 (layout [b][cc16][1026][5][32])
__global__ __launch_bounds__(256) void zero_h1_edges(short* __restrict__ h1) {
  short* base = h1 + (size_t)blockIdx.x * 164160;
  for (int i = threadIdx.x; i < 160; i += 256) {
    base[i] = 0;
    base[1025 * 160 + i] = 0;
  }
}

// ---------------------------------------------------------------------------
// conv1 (256->512, 1x12) + pool3 + relu via MFMA GEMM, counted-vmcnt pipeline.
// h0 [b][cc8][t][w28][unit^swz] -> h1 [b][cc16][tslot1026][w5][unit^swz]
// Block: co_tile=128, t_tile=32, 8 waves, wave tile 64co x 128col.
// 48 steps (8 ci-chunks x 6 kw-groups of 2). Per step: issue next step's
// loads (A 2/wave, +X 7/wave at chunk boundary), s_waitcnt vmcnt(COUNTED)
// (prefetch stays in flight!), s_barrier, 64 MFMA/wave, s_barrier.
// LDS: X dbuf 2x56KB + A dbuf 2x16KB = 144KB.
// ---------------------------------------------------------------------------
__global__ __launch_bounds__(512) void conv1_kernel(
    const short* __restrict__ h0, const short* __restrict__ wt1,
    const float* __restrict__ bias, short* __restrict__ h1) {
  const int b = blockIdx.x >> 5;
  const int t0 = (blockIdx.x & 31) * 32;
  const int co0 = blockIdx.y * 128;
  __shared__ short XsF[2][28672];   // 57344 B each: 896 rows x 4 units
  __shared__ short AsF[2][8192];    // 2kw x 512 units
  const int tid = threadIdx.x;
  const int lane = tid & 63;
  const int wid = tid >> 6;
  const int wm = wid >> 2;   // 0..1  (64 co each)
  const int wn = wid & 3;    // 0..3  (8 t each)
  const int l15 = lane & 15, lg = lane >> 4;

  const f32x4 zf = {0.f, 0.f, 0.f, 0.f};
  f32x4 acc[4][8];
#pragma unroll
  for (int i = 0; i < 4; ++i)
#pragma unroll
    for (int j = 0; j < 8; ++j) acc[i][j] = zf;

  auto stageX = [&](int cc, int buf) {
    const short* xs = h0 + ((size_t)(b * 8 + cc) * 1024 + t0) * 896;
#pragma unroll
    for (int i = 0; i < 7; ++i) {
      const int v = wid * 7 + i;   // 0..55, uniform 7 per wave
      gld16(xs + v * 512 + lane * 8, &XsF[buf][v * 512]);
    }
  };
  auto stageA = [&](int cc, int g, int buf) {
#pragma unroll
    for (int i = 0; i < 2; ++i) {
      const int u = wid * 2 + i;      // 0..15, uniform 2 per wave
      const int kwl = u >> 3, r = u & 7;
      gld16(wt1 + ((size_t)((cc * 12 + g * 2 + kwl) * 512) + co0) * 32 +
                r * 512 + lane * 8,
            &AsF[buf][kwl * 4096 + r * 512]);
    }
  };

  stageX(0, 0);
  stageA(0, 0, 0);
  asm volatile("s_waitcnt vmcnt(0)" ::: "memory");
  __builtin_amdgcn_s_barrier();

  for (int s = 0; s < 48; ++s) {
    const int cc = s / 6, g = s - cc * 6;
    if (s < 47) {
      const int s1 = s + 1;
      const int cc1 = s1 / 6, g1 = s1 - cc1 * 6;
      stageA(cc1, g1, s1 & 1);
      if (g1 == 0) {
        stageX(cc1, cc1 & 1);
        asm volatile("s_waitcnt vmcnt(9)" ::: "memory");   // 2 A + 7 X new
      } else {
        asm volatile("s_waitcnt vmcnt(2)" ::: "memory");   // 2 A new
      }
    } else {
      asm volatile("s_waitcnt vmcnt(0)" ::: "memory");
    }
    __builtin_amdgcn_s_barrier();
    const short* Xb = XsF[cc & 1];
    const short* Ab = AsF[s & 1];
#pragma unroll
    for (int j = 0; j < 2; ++j) {
      const int kw = g * 2 + j;
      bf16x8 a[4];
#pragma unroll
      for (int sm = 0; sm < 4; ++sm) {
        const int co_l = wm * 64 + sm * 16 + l15;
        a[sm] = *reinterpret_cast<const bf16x8*>(
            &Ab[(j * 512 + co_l * 4 + (lg ^ ((co_l >> 1) & 3))) * 8]);
      }
#pragma unroll
      for (int sn = 0; sn < 8; ++sn) {
        const int row = (wn * 8 + sn) * 28 + l15 + kw;
        bf16x8 bf = *reinterpret_cast<const bf16x8*>(
            &Xb[(row * 4 + (lg ^ ((row >> 1) & 3))) * 8]);
#pragma unroll
        for (int sm = 0; sm < 4; ++sm)
          acc[sm][sn] = __builtin_amdgcn_mfma_f32_16x16x32_bf16(a[sm], bf, acc[sm][sn], 0, 0, 0);
      }
    }
    asm volatile("" ::: "memory");
    __builtin_amdgcn_s_barrier();
  }
  // epilogue: pool w-triples (within 16-lane groups) + bias + relu
  const int basel = lane & 48;
  const int wsrc = (l15 < 5) ? 3 * l15 : 0;
#pragma unroll
  for (int sm = 0; sm < 4; ++sm)
#pragma unroll
    for (int sn = 0; sn < 8; ++sn) {
      const int t = t0 + wn * 8 + sn;
#pragma unroll
      for (int r = 0; r < 4; ++r) {
        float val = acc[sm][sn][r];
        float v0 = __shfl(val, basel + wsrc);
        float v1 = __shfl(val, basel + wsrc + 1);
        float v2 = __shfl(val, basel + wsrc + 2);
        if (l15 < 5) {
          const int co = co0 + wm * 64 + sm * 16 + lg * 4 + r;
          float p = fmaxf(fmaxf(v0, v1), v2) + bias[co];
          const int cc2 = co >> 5, q = (co >> 3) & 3, e = co & 7;
          const int row_g = (t + 1) * 5 + l15;
          h1[((size_t)(b * 16 + cc2) * 1026 + (t + 1)) * 160 + l15 * 32 +
             (q ^ ((row_g >> 1) & 3)) * 8 + e] = f2bf(fmaxf(p, 0.f));
        }
      }
    }
}

// ---------------------------------------------------------------------------
// conv2 (512->512, 3x3, pad t +-1) + pool3 + relu, counted-vmcnt pipeline ->
// emb_in fp32 [b][t][512].
// Block: co_tile=128, t_tile=32 (96 cols = t*3+w). 8 waves (4co x 2col).
// 48 steps (16 ci-chunks x 3 tap-rows). X staging non-uniform (waves 0-2: 2
// loads, 3-7: 1) -> wave-uniform-branched vmcnt immediates. LDS 70KB.
// ---------------------------------------------------------------------------
__global__ __launch_bounds__(512) void conv2_kernel(
    const short* __restrict__ h1, const short* __restrict__ wt2,
    const float* __restrict__ bias, float* __restrict__ emb_in) {
  const int b = blockIdx.x >> 5;
  const int t0 = (blockIdx.x & 31) * 32;
  const int co0 = blockIdx.y * 128;
  __shared__ __align__(16) short smem2[35840];  // 71680 B
  // layout: X buf0 @0, X buf1 @5632, A buf0 @11264, A buf1 @23552 (shorts)
  const int tid = threadIdx.x;
  const int lane = tid & 63;
  const int wid = tid >> 6;
  const int wm = wid >> 1;  // 0..3 (32 co each)
  const int wn = wid & 1;   // 0..1 (48 cols each)
  const int l15 = lane & 15, lg = lane >> 4;
  const f32x4 zf = {0.f, 0.f, 0.f, 0.f};
  f32x4 acc[2][3];
#pragma unroll
  for (int i = 0; i < 2; ++i)
#pragma unroll
    for (int j = 0; j < 3; ++j) acc[i][j] = zf;
  int tl[3], dwl[3];
#pragma unroll
  for (int sn = 0; sn < 3; ++sn) {
    const int c = wn * 48 + sn * 16 + l15;
    tl[sn] = c / 3;
    dwl[sn] = c - tl[sn] * 3;
  }

  auto stageX = [&](int cc, int buf) {
    const short* xs = h1 + ((size_t)(b * 16 + cc) * 1026 + t0) * 160;
#pragma unroll
    for (int i = 0; i < 2; ++i) {
      const int v = wid + 8 * i;
      if (v < 11) gld16(xs + v * 512 + lane * 8, &smem2[buf * 5632 + v * 512]);
    }
  };
  auto stageA = [&](int cc, int g, int buf) {
#pragma unroll
    for (int i = 0; i < 3; ++i) {
      const int u = wid * 3 + i;      // 0..23, uniform 3 per wave
      const int pl = u >> 3, r = u & 7;
      gld16(wt2 + ((size_t)((cc * 9 + g * 3 + pl) * 512) + co0) * 32 +
                r * 512 + lane * 8,
            &smem2[11264 + buf * 12288 + pl * 4096 + r * 512]);
    }
  };

  stageX(0, 0);
  stageA(0, 0, 0);
  asm volatile("s_waitcnt vmcnt(0)" ::: "memory");
  __builtin_amdgcn_s_barrier();

  for (int s = 0; s < 48; ++s) {
    const int cc = s / 3, g = s - cc * 3;
    if (s < 47) {
      const int s1 = s + 1;
      const int cc1 = s1 / 3, g1 = s1 - cc1 * 3;
      stageA(cc1, g1, s1 & 1);
      if (g1 == 0) {
        stageX(cc1, cc1 & 1);
        if (wid < 3) asm volatile("s_waitcnt vmcnt(5)" ::: "memory");  // 3A+2X
        else         asm volatile("s_waitcnt vmcnt(4)" ::: "memory");  // 3A+1X
      } else {
        asm volatile("s_waitcnt vmcnt(3)" ::: "memory");               // 3A
      }
    } else {
      asm volatile("s_waitcnt vmcnt(0)" ::: "memory");
    }
    __builtin_amdgcn_s_barrier();
    const short* Xb = &smem2[(cc & 1) * 5632];
    const short* Ab = &smem2[11264 + (s & 1) * 12288];
#pragma unroll
    for (int j = 0; j < 3; ++j) {   // p = g*3+j -> dt=g, dw=j
      bf16x8 a[2];
#pragma unroll
      for (int sm = 0; sm < 2; ++sm) {
        const int co_l = wm * 32 + sm * 16 + l15;
        a[sm] = *reinterpret_cast<const bf16x8*>(
            &Ab[(j * 512 + co_l * 4 + (lg ^ ((co_l >> 1) & 3))) * 8]);
      }
#pragma unroll
      for (int sn = 0; sn < 3; ++sn) {
        const int row = (tl[sn] + g) * 5 + dwl[sn] + j;
        bf16x8 xv = *reinterpret_cast<const bf16x8*>(
            &Xb[(row * 4 + (lg ^ ((row >> 1) & 3))) * 8]);
#pragma unroll
        for (int sm = 0; sm < 2; ++sm)
          acc[sm][sn] = __builtin_amdgcn_mfma_f32_16x16x32_bf16(a[sm], xv, acc[sm][sn], 0, 0, 0);
      }
    }
    asm volatile("" ::: "memory");
    __builtin_amdgcn_s_barrier();
  }
  float(*Ds)[100] = reinterpret_cast<float(*)[100]>(smem2);  // epilogue overlay
#pragma unroll
  for (int sm = 0; sm < 2; ++sm)
#pragma unroll
    for (int sn = 0; sn < 3; ++sn)
#pragma unroll
      for (int r = 0; r < 4; ++r)
        Ds[wm * 32 + sm * 16 + lg * 4 + r][wn * 48 + sn * 16 + l15] = acc[sm][sn][r];
  __syncthreads();
  for (int e = tid; e < 4096; e += 512) {
    const int co = e & 127, tt = e >> 7;
    float m = fmaxf(fmaxf(Ds[co][tt * 3], Ds[co][tt * 3 + 1]), Ds[co][tt * 3 + 2]) + bias[co0 + co];
    emb_in[((size_t)(b * 1024) + t0 + tt) * 512 + co0 + co] = fmaxf(m, 0.f);
  }
}

// ---------------------------------------------------------------------------
// LayerNorm kernels. wave-per-row (512 cols, 8 per lane).
// ---------------------------------------------------------------------------
__global__ __launch_bounds__(256) void ln_double_kernel(
    const float* __restrict__ x, const float* __restrict__ g0,
    const float* __restrict__ b0, const float* __restrict__ g1,
    const float* __restrict__ b1, float* __restrict__ o0, float* __restrict__ o1) {
  const int row = blockIdx.x * 4 + (threadIdx.x >> 6);
  const int lane = threadIdx.x & 63;
  const float* xr = x + (size_t)row * 512;
  float v[8];
#pragma unroll
  for (int j = 0; j < 8; ++j) v[j] = xr[j * 64 + lane];
  float s = 0;
#pragma unroll
  for (int j = 0; j < 8; ++j) s += v[j];
  s = wave_sum(s);
  const float mean = s * (1.f / 512.f);
  float q = 0;
#pragma unroll
  for (int j = 0; j < 8; ++j) { float d = v[j] - mean; q += d * d; }
  q = wave_sum(q);
  const float rs = rsqrtf(q * (1.f / 512.f) + 1e-5f);
#pragma unroll
  for (int j = 0; j < 8; ++j) {
    const int ci = j * 64 + lane;
    float e = (v[j] - mean) * rs * g0[ci] + b0[ci];
    o0[(size_t)row * 512 + ci] = e;
    v[j] = e;
  }
  s = 0;
#pragma unroll
  for (int j = 0; j < 8; ++j) s += v[j];
  s = wave_sum(s);
  const float mean2 = s * (1.f / 512.f);
  q = 0;
#pragma unroll
  for (int j = 0; j < 8; ++j) { float d = v[j] - mean2; q += d * d; }
  q = wave_sum(q);
  const float rs2 = rsqrtf(q * (1.f / 512.f) + 1e-5f);
#pragma unroll
  for (int j = 0; j < 8; ++j) {
    const int ci = j * 64 + lane;
    o1[(size_t)row * 512 + ci] = (v[j] - mean2) * rs2 * g1[ci] + b1[ci];
  }
}

__global__ __launch_bounds__(256) void ln_kernel(
    const float* __restrict__ x, const float* __restrict__ g,
    const float* __restrict__ b, float* __restrict__ o) {
  const int row = blockIdx.x * 4 + (threadIdx.x >> 6);
  const int lane = threadIdx.x & 63;
  const float* xr = x + (size_t)row * 512;
  float v[8];
#pragma unroll
  for (int j = 0; j < 8; ++j) v[j] = xr[j * 64 + lane];
  float s = 0;
#pragma unroll
  for (int j = 0; j < 8; ++j) s += v[j];
  s = wave_sum(s);
  const float mean = s * (1.f / 512.f);
  float q = 0;
#pragma unroll
  for (int j = 0; j < 8; ++j) { float d = v[j] - mean; q += d * d; }
  q = wave_sum(q);
  const float rs = rsqrtf(q * (1.f / 512.f) + 1e-5f);
#pragma unroll
  for (int j = 0; j < 8; ++j) {
    const int ci = j * 64 + lane;
    o[(size_t)row * 512 + ci] = (v[j] - mean) * rs * g[ci] + b[ci];
  }
}

// ---------------------------------------------------------------------------
// 1D neighborhood attention (K=7) with rpb. q,k,v fp32 [b][t][h*64+d]
// (q pre-scaled by 1/8 in its GEMM). wave per (b,h,t); lane = d.
// ---------------------------------------------------------------------------
__global__ __launch_bounds__(256) void na1d_kernel(
    const float* __restrict__ q, const float* __restrict__ k,
    const float* __restrict__ v, const float* __restrict__ rpb,
    float* __restrict__ ctx) {
  const int W = blockIdx.x * 4 + (threadIdx.x >> 6);
  const int lane = threadIdx.x & 63;
  const int b = W >> 13, h = (W >> 10) & 7, t = W & 1023;
  int ni = t - 3;
  ni = ni < 0 ? 0 : (ni > 1017 ? 1017 : ni);
  const size_t base = (size_t)(b * 1024) * 512 + h * 64;
  const float qv = q[base + (size_t)t * 512 + lane];
  const float* kb = k + base + (size_t)ni * 512;
  float s[7];
#pragma unroll
  for (int j = 0; j < 7; ++j) {
    float pd = qv * kb[j * 512 + lane];
    pd = wave_sum(pd);
    s[j] = pd + rpb[h * 13 + (ni + j - t + 6)];
  }
  float mx = s[0];
#pragma unroll
  for (int j = 1; j < 7; ++j) mx = fmaxf(mx, s[j]);
  float den = 0;
#pragma unroll
  for (int j = 0; j < 7; ++j) { s[j] = expf(s[j] - mx); den += s[j]; }
  const float inv = 1.f / den;
  const float* vb = v + base + (size_t)ni * 512;
  float o = 0;
#pragma unroll
  for (int j = 0; j < 7; ++j) o += s[j] * vb[j * 512 + lane];
  ctx[base + (size_t)t * 512 + lane] = o * inv;
}

// ---------------------------------------------------------------------------
// Transformer GEMM: C[M=4096][N] = A[M][K] (fp32) x Wt[N][K] (bf16) + bias,
// EPI: 0 = bias, 1 = bias then *0.125 (q), 2 = bias+gelu, 3 = bias+residual.
// Tile 128x64, 4 waves 2x2, BK=32.
// ---------------------------------------------------------------------------
template <int EPI>
__global__ __launch_bounds__(256) void gemm_tf(
    const float* __restrict__ A, const short* __restrict__ Wt,
    const float* __restrict__ bias, const float* __restrict__ res,
    float* __restrict__ C, int K, int N) {
  const int m0 = blockIdx.x * 128, n0 = blockIdx.y * 64;
  __shared__ short Asm[128][40];
  __shared__ short Bsm[64][40];
  const int tid = threadIdx.x;
  const int wid = tid >> 6, lane = tid & 63;
  const int wm = wid >> 1, wn = wid & 1;
  const int l15 = lane & 15, lg = lane >> 4;
  const f32x4 zf = {0.f, 0.f, 0.f, 0.f};
  f32x4 acc[4][2];
#pragma unroll
  for (int i = 0; i < 4; ++i) { acc[i][0] = zf; acc[i][1] = zf; }
  const int ar = tid >> 1, ahf = (tid & 1) * 16;
  for (int k0 = 0; k0 < K; k0 += 32) {
    __syncthreads();
    {
      const float4* s = reinterpret_cast<const float4*>(&A[(size_t)(m0 + ar) * K + k0 + ahf]);
      float4 f0 = s[0], f1 = s[1], f2 = s[2], f3 = s[3];
      short* d = &Asm[ar][ahf];
      d[0] = f2bf(f0.x);  d[1] = f2bf(f0.y);  d[2] = f2bf(f0.z);  d[3] = f2bf(f0.w);
      d[4] = f2bf(f1.x);  d[5] = f2bf(f1.y);  d[6] = f2bf(f1.z);  d[7] = f2bf(f1.w);
      d[8] = f2bf(f2.x);  d[9] = f2bf(f2.y);  d[10] = f2bf(f2.z); d[11] = f2bf(f2.w);
      d[12] = f2bf(f3.x); d[13] = f2bf(f3.y); d[14] = f2bf(f3.z); d[15] = f2bf(f3.w);
    }
    if (tid < 128) {
      const int br = tid >> 1, bhf = (tid & 1) * 16;
      const int4* s = reinterpret_cast<const int4*>(&Wt[(size_t)(n0 + br) * K + k0 + bhf]);
      int4* d = reinterpret_cast<int4*>(&Bsm[br][bhf]);
      d[0] = s[0];
      d[1] = s[1];
    }
    __syncthreads();
    bf16x8 bfr[2];
#pragma unroll
    for (int sn = 0; sn < 2; ++sn)
      bfr[sn] = *reinterpret_cast<const bf16x8*>(&Bsm[wn * 32 + sn * 16 + l15][lg * 8]);
#pragma unroll
    for (int sm = 0; sm < 4; ++sm) {
      bf16x8 a = *reinterpret_cast<const bf16x8*>(&Asm[wm * 64 + sm * 16 + l15][lg * 8]);
#pragma unroll
      for (int sn = 0; sn < 2; ++sn)
        acc[sm][sn] = __builtin_amdgcn_mfma_f32_16x16x32_bf16(a, bfr[sn], acc[sm][sn], 0, 0, 0);
    }
  }
#pragma unroll
  for (int sm = 0; sm < 4; ++sm)
#pragma unroll
    for (int sn = 0; sn < 2; ++sn)
#pragma unroll
      for (int r = 0; r < 4; ++r) {
        const int m = m0 + wm * 64 + sm * 16 + lg * 4 + r;
        const int n = n0 + wn * 32 + sn * 16 + l15;
        float val = acc[sm][sn][r] + bias[n];
        if (EPI == 1) val *= 0.125f;
        if (EPI == 2) val = 0.5f * val * (1.f + erff(val * 0.70710678f));
        if (EPI == 3) val += res[(size_t)m * N + n];
        C[(size_t)m * N + n] = val;
      }
}

// ---------------------------------------------------------------------------
extern "C" void kernel_launch(void* const* d_in, const int* in_sizes, int n_in,
                              void* d_out, int out_size, void* d_ws, size_t ws_size,
                              hipStream_t stream) {
  (void)in_sizes; (void)n_in; (void)out_size;
  const float* x        = (const float*)d_in[0];
  const float* conv0_w  = (const float*)d_in[1];
  const float* conv0_b  = (const float*)d_in[2];
  const float* conv1_w  = (const float*)d_in[3];
  const float* conv1_b  = (const float*)d_in[4];
  const float* conv2_w  = (const float*)d_in[5];
  const float* conv2_b  = (const float*)d_in[6];
  const float* emb_ln_g = (const float*)d_in[7];
  const float* emb_ln_b = (const float*)d_in[8];
  const float* q_w  = (const float*)d_in[9];
  const float* q_b  = (const float*)d_in[10];
  const float* k_w  = (const float*)d_in[11];
  const float* k_b  = (const float*)d_in[12];
  const float* v_w  = (const float*)d_in[13];
  const float* v_b  = (const float*)d_in[14];
  const float* rpb  = (const float*)d_in[15];
  const float* ao_w = (const float*)d_in[16];
  const float* ao_b = (const float*)d_in[17];
  const float* ln1_g = (const float*)d_in[18];
  const float* ln1_b = (const float*)d_in[19];
  const float* ln2_g = (const float*)d_in[20];
  const float* ln2_b = (const float*)d_in[21];
  const float* m1_w = (const float*)d_in[22];
  const float* m1_b = (const float*)d_in[23];
  const float* m2_w = (const float*)d_in[24];
  const float* m2_b = (const float*)d_in[25];

  char* ws = (char*)d_ws;
  size_t off = 0;
  auto alloc = [&](size_t bytes) -> char* {
    char* p = ws + off;
    off += (bytes + 255) & ~(size_t)255;
    return p;
  };
  short* h0   = (short*)alloc(4ull * 8 * 1024 * 896 * 2);     // 58.7 MB
  short* h1   = (short*)alloc(4ull * 16 * 1026 * 160 * 2);    // 21.0 MB
  float* embi = (float*)alloc(4ull * 1024 * 512 * 4);
  float* emb  = (float*)alloc(4ull * 1024 * 512 * 4);
  float* hs1  = (float*)alloc(4ull * 1024 * 512 * 4);
  float* qb   = (float*)alloc(4ull * 1024 * 512 * 4);
  float* kb   = (float*)alloc(4ull * 1024 * 512 * 4);
  float* vb   = (float*)alloc(4ull * 1024 * 512 * 4);
  float* ctx  = (float*)alloc(4ull * 1024 * 512 * 4);
  float* hs   = (float*)alloc(4ull * 1024 * 512 * 4);
  short* wt1  = (short*)alloc(512ull * 12 * 256 * 2);
  short* wt2  = (short*)alloc(512ull * 9 * 512 * 2);
  short* wtq  = (short*)alloc(512ull * 512 * 2);
  short* wtk  = (short*)alloc(512ull * 512 * 2);
  short* wtv  = (short*)alloc(512ull * 512 * 2);
  short* wtao = (short*)alloc(512ull * 512 * 2);
  short* wtm1 = (short*)alloc(2048ull * 512 * 2);
  short* wtm2 = (short*)alloc(512ull * 2048 * 2);
  if (ws_size < off) return;  // fail visibly (poisoned output) instead of OOB
  float* mid  = (float*)h0;   // reuse: 33.5 MB <= 58.7 MB, h0 dead after conv1
  float* ln2o = embi;         // reuse: embi dead after ln_double
  float* outp = (float*)d_out;

  prep_w1<<<512, 256, 0, stream>>>(conv1_w, wt1);
  prep_w2<<<512, 256, 0, stream>>>(conv2_w, wt2);
  zero_h1_edges<<<64, 256, 0, stream>>>(h1);
  dim3 tb(32, 8);
  prep_wt<<<dim3(16, 16), tb, 0, stream>>>(q_w, wtq, 512, 512);
  prep_wt<<<dim3(16, 16), tb, 0, stream>>>(k_w, wtk, 512, 512);
  prep_wt<<<dim3(16, 16), tb, 0, stream>>>(v_w, wtv, 512, 512);
  prep_wt<<<dim3(16, 16), tb, 0, stream>>>(ao_w, wtao, 512, 512);
  prep_wt<<<dim3(16, 64), tb, 0, stream>>>(m1_w, wtm1, 512, 2048);
  prep_wt<<<dim3(64, 16), tb, 0, stream>>>(m2_w, wtm2, 2048, 512);

  conv0_kernel<<<4096, 256, 0, stream>>>(x, conv0_w, conv0_b, h0);
  conv1_kernel<<<dim3(128, 4), 512, 0, stream>>>(h0, wt1, conv1_b, h1);
  conv2_kernel<<<dim3(128, 4), 512, 0, stream>>>(h1, wt2, conv2_b, embi);
  ln_double_kernel<<<1024, 256, 0, stream>>>(embi, emb_ln_g, emb_ln_b, ln1_g, ln1_b, emb, hs1);
  gemm_tf<1><<<dim3(32, 8), 256, 0, stream>>>(hs1, wtq, q_b, nullptr, qb, 512, 512);
  gemm_tf<0><<<dim3(32, 8), 256, 0, stream>>>(hs1, wtk, k_b, nullptr, kb, 512, 512);
  gemm_tf<0><<<dim3(32, 8), 256, 0, stream>>>(hs1, wtv, v_b, nullptr, vb, 512, 512);
  na1d_kernel<<<8192, 256, 0, stream>>>(qb, kb, vb, rpb, ctx);
  gemm_tf<3><<<dim3(32, 8), 256, 0, stream>>>(ctx, wtao, ao_b, emb, hs, 512, 512);
  ln_kernel<<<1024, 256, 0, stream>>>(hs, ln2_g, ln2_b, ln2o);
  gemm_tf<2><<<dim3(32, 32), 256, 0, stream>>>(ln2o, wtm1, m1_b, nullptr, mid, 512, 2048);
  gemm_tf<3><<<dim3(32, 8), 256, 0, stream>>>(mid, wtm2, m2_b, hs, outp, 2048, 512);
}